// Round 2
// baseline (5677.935 us; speedup 1.0000x reference)
//
#include <hip/hip_runtime.h>

#define NN 50000
#define EE 800000
#define BB 1000

// ---------------- degree / norm ----------------
__global__ void k_deg(const int* __restrict__ src, const float* __restrict__ ew,
                      float* __restrict__ deg) {
    int e = blockIdx.x * 256 + threadIdx.x;
    if (e < EE) atomicAdd(&deg[src[e]], ew[e]);
}

__global__ void k_dinv(float* __restrict__ deg) {
    int i = blockIdx.x * 256 + threadIdx.x;
    if (i < NN) {
        float d = deg[i];
        deg[i] = d > 0.f ? rsqrtf(d) : 0.f;
    }
}

__global__ void k_wnorm(const int* __restrict__ src, const int* __restrict__ dst,
                        const float* __restrict__ ew, const float* __restrict__ dinv,
                        float* __restrict__ wn) {
    int e = blockIdx.x * 256 + threadIdx.x;
    if (e < EE) wn[e] = dinv[src[e]] * ew[e] * dinv[dst[e]];
}

// ---------------- build xin = [z | x] ----------------
__global__ void k_build_xin(const float* __restrict__ z, const float* __restrict__ x,
                            float* __restrict__ xin) {
    int i = blockIdx.x * 256 + threadIdx.x;
    if (i >= NN * 96) return;
    int n = i / 96, c = i % 96;
    xin[i] = (c < 64) ? z[n * 64 + c] : x[n * 32 + (c - 64)];
}

__global__ void k_neg(const float* __restrict__ in, float* __restrict__ out, int n) {
    int i = blockIdx.x * 256 + threadIdx.x;
    if (i < n) out[i] = -in[i];
}

// ---------------- edge propagation: out[dst] += -SCALE * wn * t[src] ----------------
template <int C, int SCALE>
__global__ void k_prop(const float* __restrict__ t, float* __restrict__ out,
                       const int* __restrict__ src, const int* __restrict__ dst,
                       const float* __restrict__ wn) {
    constexpr int CG = C / 4;
    int idx = blockIdx.x * 256 + threadIdx.x;
    if (idx >= EE * CG) return;
    int e = idx / CG;
    int cg = (idx - e * CG) * 4;
    float w = -(float)SCALE * wn[e];
    const float4 v = *(const float4*)(t + (size_t)src[e] * C + cg);
    float* o = out + (size_t)dst[e] * C + cg;
    atomicAdd(o + 0, w * v.x);
    atomicAdd(o + 1, w * v.y);
    atomicAdd(o + 2, w * v.z);
    atomicAdd(o + 3, w * v.w);
}

// ---------------- fused gate GEMM: Z, hr = sigmoid(R)*h, Hx ----------------
__global__ __launch_bounds__(256) void k_gates(
    const float* __restrict__ xin, const float* __restrict__ t1x, const float* __restrict__ t2x,
    const float* __restrict__ h, const float* __restrict__ t1h, const float* __restrict__ t2h,
    const float* __restrict__ Wxz, const float* __restrict__ bxz,
    const float* __restrict__ Whz, const float* __restrict__ bhz,
    const float* __restrict__ Wxr, const float* __restrict__ bxr,
    const float* __restrict__ Whr, const float* __restrict__ bhr,
    const float* __restrict__ Wxh, const float* __restrict__ bxh,
    float* __restrict__ Z, float* __restrict__ hr, float* __restrict__ Hx) {
    int t = blockIdx.x * 256 + threadIdx.x;
    int r = t >> 6, c = t & 63;
    if (r >= NN) return;

    const float* xr0 = xin + (size_t)r * 96;
    const float* xr1 = t1x + (size_t)r * 96;
    const float* xr2 = t2x + (size_t)r * 96;
    const float* hr0 = h + (size_t)r * 64;
    const float* hr1 = t1h + (size_t)r * 64;
    const float* hr2 = t2h + (size_t)r * 64;

    float accZ = bxz[c] + bhz[c];
    float accR = bxr[c] + bhr[c];
    float accH = bxh[c];

    for (int k = 0; k < 96; k++) {
        float x0 = xr0[k], x1 = xr1[k], x2 = xr2[k];
        int i0 = k * 64 + c;
        accZ += x0 * Wxz[i0] + x1 * Wxz[6144 + i0] + x2 * Wxz[12288 + i0];
        accR += x0 * Wxr[i0] + x1 * Wxr[6144 + i0] + x2 * Wxr[12288 + i0];
        accH += x0 * Wxh[i0] + x1 * Wxh[6144 + i0] + x2 * Wxh[12288 + i0];
    }
    for (int k = 0; k < 64; k++) {
        float h0 = hr0[k], h1 = hr1[k], h2 = hr2[k];
        int i0 = k * 64 + c;
        accZ += h0 * Whz[i0] + h1 * Whz[4096 + i0] + h2 * Whz[8192 + i0];
        accR += h0 * Whr[i0] + h1 * Whr[4096 + i0] + h2 * Whr[8192 + i0];
    }
    float Zv = 1.f / (1.f + expf(-accZ));
    float Rv = 1.f / (1.f + expf(-accR));
    Z[(size_t)r * 64 + c] = Zv;
    hr[(size_t)r * 64 + c] = Rv * hr0[c];
    Hx[(size_t)r * 64 + c] = accH;
}

// ---------------- final: Ht = tanh(Hx + cheb(hr)@Whh), h' = Z*h + (1-Z)*Ht ----------------
__global__ __launch_bounds__(256) void k_final(
    const float* __restrict__ hr, const float* __restrict__ t1hr, const float* __restrict__ t2hr,
    const float* __restrict__ Hx, const float* __restrict__ Z, const float* __restrict__ h,
    const float* __restrict__ Whh, const float* __restrict__ bhh,
    float* __restrict__ outh) {
    int t = blockIdx.x * 256 + threadIdx.x;
    int r = t >> 6, c = t & 63;
    if (r >= NN) return;
    const float* a0 = hr + (size_t)r * 64;
    const float* a1 = t1hr + (size_t)r * 64;
    const float* a2 = t2hr + (size_t)r * 64;
    float acc = bhh[c];
    for (int k = 0; k < 64; k++) {
        int i0 = k * 64 + c;
        acc += a0[k] * Whh[i0] + a1[k] * Whh[4096 + i0] + a2[k] * Whh[8192 + i0];
    }
    size_t i = (size_t)r * 64 + c;
    float ht = tanhf(Hx[i] + acc);
    float zv = Z[i];
    float hn = zv * h[i] + (1.f - zv) * ht;
    outh[i] = hn;
}

// ---------------- graph embedding tail ----------------
__global__ void k_gemb(const float* __restrict__ z, const int* __restrict__ batch,
                       float* __restrict__ gemb) {
    int t = blockIdx.x * 256 + threadIdx.x;
    if (t >= NN * 64) return;
    int n = t >> 6, c = t & 63;
    atomicAdd(&gemb[(size_t)batch[n] * 64 + c], z[(size_t)n * 64 + c]);
}

__global__ __launch_bounds__(256) void k_fused(
    const float* __restrict__ u, const float* __restrict__ Wg, const float* __restrict__ bg,
    const float* __restrict__ gemb, float* __restrict__ out) {
    int t = blockIdx.x * 256 + threadIdx.x;
    int r = t >> 6, c = t & 63;
    if (r >= BB) return;
    float acc = bg[c];
    const float* ur = u + (size_t)r * 64;
    for (int k = 0; k < 64; k++) acc += ur[k] * Wg[k * 64 + c];
    acc = fmaxf(acc, 0.f);
    out[(size_t)r * 128 + c] = gemb[(size_t)r * 64 + c];
    out[(size_t)r * 128 + 64 + c] = acc;
}

extern "C" void kernel_launch(void* const* d_in, const int* in_sizes, int n_in,
                              void* d_out, int out_size, void* d_ws, size_t ws_size,
                              hipStream_t stream) {
    const float* x  = (const float*)d_in[0];
    const float* u  = (const float*)d_in[1];
    const float* z  = (const float*)d_in[2];
    const int*   ei = (const int*)d_in[3];
    const float* ew = (const float*)d_in[4];
    const int* batch = (const int*)d_in[5];
    const float* ph = (const float*)d_in[7];
    const float *Wxz = (const float*)d_in[8],  *bxz = (const float*)d_in[9];
    const float *Whz = (const float*)d_in[10], *bhz = (const float*)d_in[11];
    const float *Wxr = (const float*)d_in[12], *bxr = (const float*)d_in[13];
    const float *Whr = (const float*)d_in[14], *bhr = (const float*)d_in[15];
    const float *Wxh = (const float*)d_in[16], *bxh = (const float*)d_in[17];
    const float *Whh = (const float*)d_in[18], *bhh = (const float*)d_in[19];
    const float *Wg  = (const float*)d_in[20], *bg  = (const float*)d_in[21];
    const int* src = ei;
    const int* dst = ei + EE;

    float* ws = (float*)d_ws;
    size_t o = 0;
    float* deg  = ws + o; o += NN;          // becomes dinv in place
    float* wn   = ws + o; o += EE;
    float* xin  = ws + o; o += (size_t)NN * 96;
    float* t1x  = ws + o; o += (size_t)NN * 96;
    float* t2x  = ws + o; o += (size_t)NN * 96;
    float* t1h  = ws + o; o += (size_t)NN * 64;
    float* t2h  = ws + o; o += (size_t)NN * 64;
    float* hr   = ws + o; o += (size_t)NN * 64;
    float* t1hr = ws + o; o += (size_t)NN * 64;
    float* t2hr = ws + o; o += (size_t)NN * 64;
    float* Zb   = ws + o; o += (size_t)NN * 64;
    float* Hx   = ws + o; o += (size_t)NN * 64;
    float* gemb = ws + o; o += (size_t)BB * 64;

    float* outF = (float*)d_out;               // [B,128]
    float* outH = outF + (size_t)BB * 128;     // [N,64]

    const int BLK = 256;
    const int gE = (EE + BLK - 1) / BLK;
    const int gN = (NN + BLK - 1) / BLK;
    const int gN96 = (NN * 96 + BLK - 1) / BLK;
    const int gN64 = (NN * 64 + BLK - 1) / BLK;
    const int gP96 = (EE * 24 + BLK - 1) / BLK;
    const int gP64 = (EE * 16 + BLK - 1) / BLK;

    // 1. degree / dinv / w_norm
    hipMemsetAsync(deg, 0, NN * sizeof(float), stream);
    k_deg<<<gE, BLK, 0, stream>>>(src, ew, deg);
    k_dinv<<<gN, BLK, 0, stream>>>(deg);
    k_wnorm<<<gE, BLK, 0, stream>>>(src, dst, ew, deg, wn);

    // 2. build xin (concat z|x)
    k_build_xin<<<gN96, BLK, 0, stream>>>(z, x, xin);

    // 3. Chebyshev basis for xin
    hipMemsetAsync(t1x, 0, (size_t)NN * 96 * sizeof(float), stream);
    k_prop<96, 1><<<gP96, BLK, 0, stream>>>(xin, t1x, src, dst, wn);
    k_neg<<<gN96, BLK, 0, stream>>>(xin, t2x, NN * 96);
    k_prop<96, 2><<<gP96, BLK, 0, stream>>>(t1x, t2x, src, dst, wn);

    // 4. Chebyshev basis for prev_h
    hipMemsetAsync(t1h, 0, (size_t)NN * 64 * sizeof(float), stream);
    k_prop<64, 1><<<gP64, BLK, 0, stream>>>(ph, t1h, src, dst, wn);
    k_neg<<<gN64, BLK, 0, stream>>>(ph, t2h, NN * 64);
    k_prop<64, 2><<<gP64, BLK, 0, stream>>>(t1h, t2h, src, dst, wn);

    // 5. gates: Z, hr = sigmoid(R)*prev_h, Hx
    k_gates<<<gN64, BLK, 0, stream>>>(xin, t1x, t2x, ph, t1h, t2h,
                                      Wxz, bxz, Whz, bhz, Wxr, bxr, Whr, bhr,
                                      Wxh, bxh, Zb, hr, Hx);

    // 6. Chebyshev basis for hr
    hipMemsetAsync(t1hr, 0, (size_t)NN * 64 * sizeof(float), stream);
    k_prop<64, 1><<<gP64, BLK, 0, stream>>>(hr, t1hr, src, dst, wn);
    k_neg<<<gN64, BLK, 0, stream>>>(hr, t2hr, NN * 64);
    k_prop<64, 2><<<gP64, BLK, 0, stream>>>(t1hr, t2hr, src, dst, wn);

    // 7. candidate + GRU blend -> h out
    k_final<<<gN64, BLK, 0, stream>>>(hr, t1hr, t2hr, Hx, Zb, ph, Whh, bhh, outH);

    // 8. tail: graph emb + global emb -> fused out
    hipMemsetAsync(gemb, 0, (size_t)BB * 64 * sizeof(float), stream);
    k_gemb<<<gN64, BLK, 0, stream>>>(z, batch, gemb);
    k_fused<<<(BB * 64 + BLK - 1) / BLK, BLK, 0, stream>>>(u, Wg, bg, gemb, outF);
}

// Round 3
// 1363.549 us; speedup vs baseline: 4.1641x; 4.1641x over previous
//
#include <hip/hip_runtime.h>

#define NN 50000
#define EE 800000
#define BB 1000
#define NB 196  // ceil(NN/256)

// ---------------- degree (over src) ----------------
__global__ void k_deg(const int* __restrict__ src, const float* __restrict__ ew,
                      float* __restrict__ deg) {
    int e = blockIdx.x * 256 + threadIdx.x;
    if (e < EE) atomicAdd(&deg[src[e]], ew[e]);
}

__global__ void k_dinv(float* __restrict__ deg) {
    int i = blockIdx.x * 256 + threadIdx.x;
    if (i < NN) {
        float d = deg[i];
        deg[i] = d > 0.f ? rsqrtf(d) : 0.f;
    }
}

// ---------------- CSR build: in-degree, scan, scatter ----------------
__global__ void k_indeg(const int* __restrict__ dst, int* __restrict__ cnt) {
    int e = blockIdx.x * 256 + threadIdx.x;
    if (e < EE) atomicAdd(&cnt[dst[e]], 1);
}

__global__ void k_scan1(const int* __restrict__ cnt, int* __restrict__ incl,
                        int* __restrict__ bsum) {
    __shared__ int s[256];
    int i = blockIdx.x * 256 + threadIdx.x;
    int v = (i < NN) ? cnt[i] : 0;
    s[threadIdx.x] = v;
    __syncthreads();
    for (int off = 1; off < 256; off <<= 1) {
        int t = (threadIdx.x >= off) ? s[threadIdx.x - off] : 0;
        __syncthreads();
        s[threadIdx.x] += t;
        __syncthreads();
    }
    if (i < NN) incl[i] = s[threadIdx.x];
    if (threadIdx.x == 255) bsum[blockIdx.x] = s[255];
}

__global__ void k_scan2(int* __restrict__ bsum) {
    __shared__ int s[256];
    int v = (threadIdx.x < NB) ? bsum[threadIdx.x] : 0;
    s[threadIdx.x] = v;
    __syncthreads();
    for (int off = 1; off < 256; off <<= 1) {
        int t = (threadIdx.x >= off) ? s[threadIdx.x - off] : 0;
        __syncthreads();
        s[threadIdx.x] += t;
        __syncthreads();
    }
    if (threadIdx.x < NB) bsum[threadIdx.x] = s[threadIdx.x];
}

__global__ void k_scan3(const int* __restrict__ incl, const int* __restrict__ cnt,
                        const int* __restrict__ bsum, int* __restrict__ row_ptr,
                        int* __restrict__ cursor) {
    int i = blockIdx.x * 256 + threadIdx.x;
    if (i >= NN) return;
    int off = (blockIdx.x > 0) ? bsum[blockIdx.x - 1] : 0;
    int start = off + incl[i] - cnt[i];
    row_ptr[i] = start;
    cursor[i] = start;
}

__global__ void k_scatter(const int* __restrict__ src, const int* __restrict__ dst,
                          const float* __restrict__ ew, const float* __restrict__ dinv,
                          int* __restrict__ cursor, int* __restrict__ csr_src,
                          float* __restrict__ csr_w) {
    int e = blockIdx.x * 256 + threadIdx.x;
    if (e >= EE) return;
    int d = dst[e], s = src[e];
    int pos = atomicAdd(&cursor[d], 1);
    csr_src[pos] = s;
    csr_w[pos] = dinv[s] * ew[e] * dinv[d];
}

// ---------------- build xin = [z | x] ----------------
__global__ void k_build_xin(const float* __restrict__ z, const float* __restrict__ x,
                            float* __restrict__ xin) {
    int i = blockIdx.x * 256 + threadIdx.x;
    if (i >= NN * 96) return;
    int n = i / 96, c = i % 96;
    xin[i] = (c < 64) ? z[n * 64 + c] : x[n * 32 + (c - 64)];
}

// ---------------- pull propagation ----------------
// out[r] = -SCALE * sum_e w_e * t[src_e]  (+ HB ? -base[r] : 0)
template <int C, int SCALE, bool HB, int BS>
__global__ __launch_bounds__(BS) void k_pull(
    const float* __restrict__ t, const float* __restrict__ base, float* __restrict__ out,
    const int* __restrict__ csr_src, const float* __restrict__ csr_w,
    const int* __restrict__ row_ptr, const int* __restrict__ cnt) {
    constexpr int TPR = C / 4;
    int tid = blockIdx.x * BS + threadIdx.x;
    int r = tid / TPR;
    int c4 = (tid - r * TPR) * 4;
    if (r >= NN) return;
    int s0 = row_ptr[r], n = cnt[r];
    float4 acc = {0.f, 0.f, 0.f, 0.f};
    for (int j = 0; j < n; j++) {
        int s = csr_src[s0 + j];
        float w = csr_w[s0 + j];
        const float4 v = *(const float4*)(t + (size_t)s * C + c4);
        acc.x += w * v.x;
        acc.y += w * v.y;
        acc.z += w * v.z;
        acc.w += w * v.w;
    }
    float4 o;
    const float sc = -(float)SCALE;
    if (HB) {
        const float4 b = *(const float4*)(base + (size_t)r * C + c4);
        o.x = sc * acc.x - b.x;
        o.y = sc * acc.y - b.y;
        o.z = sc * acc.z - b.z;
        o.w = sc * acc.w - b.w;
    } else {
        o.x = sc * acc.x;
        o.y = sc * acc.y;
        o.z = sc * acc.z;
        o.w = sc * acc.w;
    }
    *(float4*)(out + (size_t)r * C + c4) = o;
}

// ---------------- fused gate GEMM: Z, hr = sigmoid(R)*h, Hx ----------------
__global__ __launch_bounds__(256) void k_gates(
    const float* __restrict__ xin, const float* __restrict__ t1x, const float* __restrict__ t2x,
    const float* __restrict__ h, const float* __restrict__ t1h, const float* __restrict__ t2h,
    const float* __restrict__ Wxz, const float* __restrict__ bxz,
    const float* __restrict__ Whz, const float* __restrict__ bhz,
    const float* __restrict__ Wxr, const float* __restrict__ bxr,
    const float* __restrict__ Whr, const float* __restrict__ bhr,
    const float* __restrict__ Wxh, const float* __restrict__ bxh,
    float* __restrict__ Z, float* __restrict__ hr, float* __restrict__ Hx) {
    int t = blockIdx.x * 256 + threadIdx.x;
    int r = t >> 6, c = t & 63;
    if (r >= NN) return;

    const float* xr0 = xin + (size_t)r * 96;
    const float* xr1 = t1x + (size_t)r * 96;
    const float* xr2 = t2x + (size_t)r * 96;
    const float* hr0 = h + (size_t)r * 64;
    const float* hr1 = t1h + (size_t)r * 64;
    const float* hr2 = t2h + (size_t)r * 64;

    float accZ = bxz[c] + bhz[c];
    float accR = bxr[c] + bhr[c];
    float accH = bxh[c];

    for (int k = 0; k < 96; k++) {
        float x0 = xr0[k], x1 = xr1[k], x2 = xr2[k];
        int i0 = k * 64 + c;
        accZ += x0 * Wxz[i0] + x1 * Wxz[6144 + i0] + x2 * Wxz[12288 + i0];
        accR += x0 * Wxr[i0] + x1 * Wxr[6144 + i0] + x2 * Wxr[12288 + i0];
        accH += x0 * Wxh[i0] + x1 * Wxh[6144 + i0] + x2 * Wxh[12288 + i0];
    }
    for (int k = 0; k < 64; k++) {
        float h0 = hr0[k], h1 = hr1[k], h2 = hr2[k];
        int i0 = k * 64 + c;
        accZ += h0 * Whz[i0] + h1 * Whz[4096 + i0] + h2 * Whz[8192 + i0];
        accR += h0 * Whr[i0] + h1 * Whr[4096 + i0] + h2 * Whr[8192 + i0];
    }
    float Zv = 1.f / (1.f + expf(-accZ));
    float Rv = 1.f / (1.f + expf(-accR));
    Z[(size_t)r * 64 + c] = Zv;
    hr[(size_t)r * 64 + c] = Rv * hr0[c];
    Hx[(size_t)r * 64 + c] = accH;
}

// ---------------- final: Ht = tanh(Hx + cheb(hr)@Whh), h' = Z*h + (1-Z)*Ht ----------------
__global__ __launch_bounds__(256) void k_final(
    const float* __restrict__ hr, const float* __restrict__ t1hr, const float* __restrict__ t2hr,
    const float* __restrict__ Hx, const float* __restrict__ Z, const float* __restrict__ h,
    const float* __restrict__ Whh, const float* __restrict__ bhh,
    float* __restrict__ outh) {
    int t = blockIdx.x * 256 + threadIdx.x;
    int r = t >> 6, c = t & 63;
    if (r >= NN) return;
    const float* a0 = hr + (size_t)r * 64;
    const float* a1 = t1hr + (size_t)r * 64;
    const float* a2 = t2hr + (size_t)r * 64;
    float acc = bhh[c];
    for (int k = 0; k < 64; k++) {
        int i0 = k * 64 + c;
        acc += a0[k] * Whh[i0] + a1[k] * Whh[4096 + i0] + a2[k] * Whh[8192 + i0];
    }
    size_t i = (size_t)r * 64 + c;
    float ht = tanhf(Hx[i] + acc);
    float zv = Z[i];
    float hn = zv * h[i] + (1.f - zv) * ht;
    outh[i] = hn;
}

// ---------------- graph embedding (batch is sorted -> run-accumulate) ----------------
__global__ void k_gemb(const float* __restrict__ z, const int* __restrict__ batch,
                       float* __restrict__ gemb) {
    int wave = (blockIdx.x * 256 + threadIdx.x) >> 6;
    int lane = threadIdx.x & 63;
    int n0 = wave * 64;
    if (n0 >= NN) return;
    int nend = n0 + 64 < NN ? n0 + 64 : NN;
    float acc = 0.f;
    int cur = batch[n0];
    for (int n = n0; n < nend; n++) {
        int b = batch[n];
        if (b != cur) {
            atomicAdd(&gemb[(size_t)cur * 64 + lane], acc);
            acc = 0.f;
            cur = b;
        }
        acc += z[(size_t)n * 64 + lane];
    }
    atomicAdd(&gemb[(size_t)cur * 64 + lane], acc);
}

__global__ __launch_bounds__(256) void k_fused(
    const float* __restrict__ u, const float* __restrict__ Wg, const float* __restrict__ bg,
    const float* __restrict__ gemb, float* __restrict__ out) {
    int t = blockIdx.x * 256 + threadIdx.x;
    int r = t >> 6, c = t & 63;
    if (r >= BB) return;
    float acc = bg[c];
    const float* ur = u + (size_t)r * 64;
    for (int k = 0; k < 64; k++) acc += ur[k] * Wg[k * 64 + c];
    acc = fmaxf(acc, 0.f);
    out[(size_t)r * 128 + c] = gemb[(size_t)r * 64 + c];
    out[(size_t)r * 128 + 64 + c] = acc;
}

extern "C" void kernel_launch(void* const* d_in, const int* in_sizes, int n_in,
                              void* d_out, int out_size, void* d_ws, size_t ws_size,
                              hipStream_t stream) {
    const float* x  = (const float*)d_in[0];
    const float* u  = (const float*)d_in[1];
    const float* z  = (const float*)d_in[2];
    const int*   ei = (const int*)d_in[3];
    const float* ew = (const float*)d_in[4];
    const int* batch = (const int*)d_in[5];
    const float* ph = (const float*)d_in[7];
    const float *Wxz = (const float*)d_in[8],  *bxz = (const float*)d_in[9];
    const float *Whz = (const float*)d_in[10], *bhz = (const float*)d_in[11];
    const float *Wxr = (const float*)d_in[12], *bxr = (const float*)d_in[13];
    const float *Whr = (const float*)d_in[14], *bhr = (const float*)d_in[15];
    const float *Wxh = (const float*)d_in[16], *bxh = (const float*)d_in[17];
    const float *Whh = (const float*)d_in[18], *bhh = (const float*)d_in[19];
    const float *Wg  = (const float*)d_in[20], *bg  = (const float*)d_in[21];
    const int* src = ei;
    const int* dst = ei + EE;

    char* wsb = (char*)d_ws;
    size_t o = 0;
    auto alloc = [&](size_t elems) { void* p = wsb + o; o += elems * 4; return p; };
    float* deg     = (float*)alloc(NN);      // becomes dinv in place
    int*   cnt     = (int*)alloc(NN);
    int*   incl    = (int*)alloc(NN);
    int*   row_ptr = (int*)alloc(NN);
    int*   cursor  = (int*)alloc(NN);
    int*   bsum    = (int*)alloc(256);
    int*   csr_src = (int*)alloc(EE);
    float* csr_w   = (float*)alloc(EE);
    float* xin  = (float*)alloc((size_t)NN * 96);
    float* t1x  = (float*)alloc((size_t)NN * 96);
    float* t2x  = (float*)alloc((size_t)NN * 96);
    float* t1h  = (float*)alloc((size_t)NN * 64);
    float* t2h  = (float*)alloc((size_t)NN * 64);
    float* hr   = (float*)alloc((size_t)NN * 64);
    float* Zb   = (float*)alloc((size_t)NN * 64);
    float* Hx   = (float*)alloc((size_t)NN * 64);
    float* gemb = (float*)alloc((size_t)BB * 64);
    // hr-basis reuses t1h/t2h after k_gates consumed them
    float* t1hr = t1h;
    float* t2hr = t2h;

    float* outF = (float*)d_out;               // [B,128]
    float* outH = outF + (size_t)BB * 128;     // [N,64]

    const int BLK = 256;
    const int gE = (EE + BLK - 1) / BLK;
    const int gN = (NN + BLK - 1) / BLK;
    const int gN96 = (NN * 96 + BLK - 1) / BLK;
    const int gN64 = (NN * 64 + BLK - 1) / BLK;
    // pull grids: C=64 -> 16 thr/row, 256 blk -> 16 rows/blk; C=96 -> 24 thr/row, 192 blk -> 8 rows/blk
    const int gPull64 = (NN + 15) / 16;
    const int gPull96 = (NN + 7) / 8;

    // 1. degree / dinv
    hipMemsetAsync(deg, 0, NN * 4, stream);
    hipMemsetAsync(cnt, 0, NN * 4, stream);
    k_deg<<<gE, BLK, 0, stream>>>(src, ew, deg);
    k_dinv<<<gN, BLK, 0, stream>>>(deg);

    // 2. CSR by dst (norm folded into csr_w)
    k_indeg<<<gE, BLK, 0, stream>>>(dst, cnt);
    k_scan1<<<NB, 256, 0, stream>>>(cnt, incl, bsum);
    k_scan2<<<1, 256, 0, stream>>>(bsum);
    k_scan3<<<NB, 256, 0, stream>>>(incl, cnt, bsum, row_ptr, cursor);
    k_scatter<<<gE, BLK, 0, stream>>>(src, dst, ew, deg, cursor, csr_src, csr_w);

    // 3. xin = [z|x]
    k_build_xin<<<gN96, BLK, 0, stream>>>(z, x, xin);

    // 4. Chebyshev bases (pull, no atomics):
    //    t1 = -prop(t0);  t2 = -2*prop(t1) - t0
    k_pull<96, 1, false, 192><<<gPull96, 192, 0, stream>>>(xin, nullptr, t1x, csr_src, csr_w, row_ptr, cnt);
    k_pull<96, 2, true, 192><<<gPull96, 192, 0, stream>>>(t1x, xin, t2x, csr_src, csr_w, row_ptr, cnt);
    k_pull<64, 1, false, 256><<<gPull64, 256, 0, stream>>>(ph, nullptr, t1h, csr_src, csr_w, row_ptr, cnt);
    k_pull<64, 2, true, 256><<<gPull64, 256, 0, stream>>>(t1h, ph, t2h, csr_src, csr_w, row_ptr, cnt);

    // 5. gates: Z, hr = sigmoid(R)*prev_h, Hx
    k_gates<<<gN64, BLK, 0, stream>>>(xin, t1x, t2x, ph, t1h, t2h,
                                      Wxz, bxz, Whz, bhz, Wxr, bxr, Whr, bhr,
                                      Wxh, bxh, Zb, hr, Hx);

    // 6. Chebyshev basis for hr (reuses t1h/t2h buffers)
    k_pull<64, 1, false, 256><<<gPull64, 256, 0, stream>>>(hr, nullptr, t1hr, csr_src, csr_w, row_ptr, cnt);
    k_pull<64, 2, true, 256><<<gPull64, 256, 0, stream>>>(t1hr, hr, t2hr, csr_src, csr_w, row_ptr, cnt);

    // 7. candidate + GRU blend -> h out
    k_final<<<gN64, BLK, 0, stream>>>(hr, t1hr, t2hr, Hx, Zb, ph, Whh, bhh, outH);

    // 8. tail: graph emb + global emb -> fused out
    hipMemsetAsync(gemb, 0, (size_t)BB * 64 * 4, stream);
    k_gemb<<<gN, BLK, 0, stream>>>(z, batch, gemb);
    k_fused<<<(BB * 64 + BLK - 1) / BLK, BLK, 0, stream>>>(u, Wg, bg, gemb, outF);
}

// Round 4
// 614.289 us; speedup vs baseline: 9.2431x; 2.2197x over previous
//
#include <hip/hip_runtime.h>

#define NN 50000
#define EE 800000
#define BB 1000
#define NB 196  // ceil(NN/256)

typedef unsigned short u16;
typedef __attribute__((ext_vector_type(8))) short bf16x8;
typedef __attribute__((ext_vector_type(4))) float f32x4;

static __device__ __forceinline__ u16 f2b(float f) {
    union { float f; unsigned u; } v;
    v.f = f;
    unsigned r = v.u + 0x7fffu + ((v.u >> 16) & 1u);
    return (u16)(r >> 16);
}

// ---------------- degree (over src) ----------------
__global__ void k_deg(const int* __restrict__ src, const float* __restrict__ ew,
                      float* __restrict__ deg) {
    int e = blockIdx.x * 256 + threadIdx.x;
    if (e < EE) atomicAdd(&deg[src[e]], ew[e]);
}

__global__ void k_dinv(float* __restrict__ deg) {
    int i = blockIdx.x * 256 + threadIdx.x;
    if (i < NN) {
        float d = deg[i];
        deg[i] = d > 0.f ? rsqrtf(d) : 0.f;
    }
}

// ---------------- CSR build ----------------
__global__ void k_indeg(const int* __restrict__ dst, int* __restrict__ cnt) {
    int e = blockIdx.x * 256 + threadIdx.x;
    if (e < EE) atomicAdd(&cnt[dst[e]], 1);
}

__global__ void k_scan1(const int* __restrict__ cnt, int* __restrict__ incl,
                        int* __restrict__ bsum) {
    __shared__ int s[256];
    int i = blockIdx.x * 256 + threadIdx.x;
    int v = (i < NN) ? cnt[i] : 0;
    s[threadIdx.x] = v;
    __syncthreads();
    for (int off = 1; off < 256; off <<= 1) {
        int t = (threadIdx.x >= off) ? s[threadIdx.x - off] : 0;
        __syncthreads();
        s[threadIdx.x] += t;
        __syncthreads();
    }
    if (i < NN) incl[i] = s[threadIdx.x];
    if (threadIdx.x == 255) bsum[blockIdx.x] = s[255];
}

__global__ void k_scan2(int* __restrict__ bsum) {
    __shared__ int s[256];
    int v = (threadIdx.x < NB) ? bsum[threadIdx.x] : 0;
    s[threadIdx.x] = v;
    __syncthreads();
    for (int off = 1; off < 256; off <<= 1) {
        int t = (threadIdx.x >= off) ? s[threadIdx.x - off] : 0;
        __syncthreads();
        s[threadIdx.x] += t;
        __syncthreads();
    }
    if (threadIdx.x < NB) bsum[threadIdx.x] = s[threadIdx.x];
}

__global__ void k_scan3(const int* __restrict__ incl, const int* __restrict__ cnt,
                        const int* __restrict__ bsum, int* __restrict__ row_ptr,
                        int* __restrict__ cursor) {
    int i = blockIdx.x * 256 + threadIdx.x;
    if (i >= NN) return;
    int off = (blockIdx.x > 0) ? bsum[blockIdx.x - 1] : 0;
    int start = off + incl[i] - cnt[i];
    row_ptr[i] = start;
    cursor[i] = start;
}

__global__ void k_scatter(const int* __restrict__ src, const int* __restrict__ dst,
                          const float* __restrict__ ew, const float* __restrict__ dinv,
                          int* __restrict__ cursor, int* __restrict__ csr_src,
                          float* __restrict__ csr_w) {
    int e = blockIdx.x * 256 + threadIdx.x;
    if (e >= EE) return;
    int d = dst[e], s = src[e];
    int pos = atomicAdd(&cursor[d], 1);
    csr_src[pos] = s;
    csr_w[pos] = dinv[s] * ew[e] * dinv[d];
}

// ---------------- build xin = [z | x] (f32 + bf16 A slice) ----------------
__global__ void k_build_xin(const float* __restrict__ z, const float* __restrict__ x,
                            float* __restrict__ xin, u16* __restrict__ A) {
    int i = blockIdx.x * 256 + threadIdx.x;
    if (i >= NN * 96) return;
    int n = i / 96, c = i - n * 96;
    float v = (c < 64) ? z[n * 64 + c] : x[n * 32 + (c - 64)];
    xin[i] = v;
    A[(size_t)n * 480 + c] = f2b(v);
}

// ph -> A slice [288..352)
__global__ void k_cvt_ph(const float* __restrict__ ph, u16* __restrict__ A) {
    int i = blockIdx.x * 256 + threadIdx.x;
    if (i >= NN * 64) return;
    int r = i >> 6, c = i & 63;
    A[(size_t)r * 480 + 288 + c] = f2b(ph[i]);
}

// ---------------- weight packing to MFMA B-fragment layout ----------------
// Wp[s][ct][lane][j] = W[32s + (lane>>4)*8 + j][16*(ct&3) + (lane&15)] of gate g=ct>>2
__global__ void k_packW(const float* __restrict__ Wxz, const float* __restrict__ Wxr,
                        const float* __restrict__ Wxh, const float* __restrict__ Whz,
                        const float* __restrict__ Whr, u16* __restrict__ Wp) {
    int idx = blockIdx.x * 256 + threadIdx.x;
    if (idx >= 15 * 12 * 512) return;
    int j = idx & 7, l = (idx >> 3) & 63;
    int ct = (idx >> 9) % 12, s = (idx >> 9) / 12;
    int k = 32 * s + (l >> 4) * 8 + j;
    int g = ct >> 2;
    int c = 16 * (ct & 3) + (l & 15);
    float val;
    if (k < 288) {
        int ki = k / 96, kr = k - ki * 96;
        const float* W = (g == 0) ? Wxz : ((g == 1) ? Wxr : Wxh);
        val = W[(ki * 96 + kr) * 64 + c];
    } else if (g == 2) {
        val = 0.f;
    } else {
        int km = k - 288;
        int ki = km >> 6, kr = km & 63;
        const float* W = (g == 0) ? Whz : Whr;
        val = W[(ki * 64 + kr) * 64 + c];
    }
    Wp[idx] = f2b(val);
}

__global__ void k_packW3(const float* __restrict__ Whh, u16* __restrict__ W3p) {
    int idx = blockIdx.x * 256 + threadIdx.x;
    if (idx >= 6 * 4 * 512) return;
    int j = idx & 7, l = (idx >> 3) & 63;
    int ct = (idx >> 9) & 3, s = idx >> 11;
    int k = 32 * s + (l >> 4) * 8 + j;
    int ki = k >> 6, kr = k & 63;
    int c = 16 * ct + (l & 15);
    W3p[idx] = f2b(Whh[(ki * 64 + kr) * 64 + c]);
}

// ---------------- pull propagation ----------------
// res[r] = -SCALE * sum_e w_e * t[src_e]  (HB: - base[r]);
// writes f32 (if WF) and/or bf16 A-slice (if WB, row stride OS, outb pre-offset)
template <int C, int SCALE, bool HB, int BS, bool WF, bool WB, int OS>
__global__ __launch_bounds__(BS) void k_pull(
    const float* __restrict__ t, const float* __restrict__ base,
    float* __restrict__ outf, u16* __restrict__ outb,
    const int* __restrict__ csr_src, const float* __restrict__ csr_w,
    const int* __restrict__ row_ptr, const int* __restrict__ cnt) {
    constexpr int TPR = C / 4;
    int tid = blockIdx.x * BS + threadIdx.x;
    int r = tid / TPR;
    int c4 = (tid - r * TPR) * 4;
    if (r >= NN) return;
    int s0 = row_ptr[r], n = cnt[r];
    float4 acc = {0.f, 0.f, 0.f, 0.f};
    for (int j = 0; j < n; j++) {
        int s = csr_src[s0 + j];
        float w = csr_w[s0 + j];
        const float4 v = *(const float4*)(t + (size_t)s * C + c4);
        acc.x += w * v.x;
        acc.y += w * v.y;
        acc.z += w * v.z;
        acc.w += w * v.w;
    }
    float4 o;
    const float sc = -(float)SCALE;
    if (HB) {
        const float4 b = *(const float4*)(base + (size_t)r * C + c4);
        o.x = sc * acc.x - b.x;
        o.y = sc * acc.y - b.y;
        o.z = sc * acc.z - b.z;
        o.w = sc * acc.w - b.w;
    } else {
        o.x = sc * acc.x;
        o.y = sc * acc.y;
        o.z = sc * acc.z;
        o.w = sc * acc.w;
    }
    if (WF) *(float4*)(outf + (size_t)r * C + c4) = o;
    if (WB) {
        ushort4 p;
        p.x = f2b(o.x);
        p.y = f2b(o.y);
        p.z = f2b(o.z);
        p.w = f2b(o.w);
        *(ushort4*)(outb + (size_t)r * OS + c4) = p;
    }
}

// ---------------- gates GEMM (MFMA): [N,480]x[480,192] -> Z, hr, Hx ----------------
__global__ __launch_bounds__(256) void k_gates_mfma(
    const u16* __restrict__ A, const u16* __restrict__ Wp,
    const float* __restrict__ bxz, const float* __restrict__ bhz,
    const float* __restrict__ bxr, const float* __restrict__ bhr,
    const float* __restrict__ bxh, const float* __restrict__ ph,
    float* __restrict__ Zb, float* __restrict__ hr, float* __restrict__ Hx,
    u16* __restrict__ A3) {
    int wv = (blockIdx.x * 256 + threadIdx.x) >> 6;
    int lane = threadIdx.x & 63;
    int r0 = wv * 16;
    if (r0 >= NN) return;
    int q = lane >> 4, j0 = lane & 15;

    f32x4 acc[12];
#pragma unroll
    for (int i = 0; i < 12; i++) acc[i] = (f32x4){0.f, 0.f, 0.f, 0.f};

    const u16* arow = A + (size_t)(r0 + j0) * 480 + q * 8;
#pragma unroll
    for (int s = 0; s < 15; s++) {
        bf16x8 a = *(const bf16x8*)(arow + 32 * s);
        const u16* bp = Wp + (size_t)(s * 12) * 512 + lane * 8;
#pragma unroll
        for (int ct = 0; ct < 12; ct++) {
            bf16x8 b = *(const bf16x8*)(bp + ct * 512);
            acc[ct] = __builtin_amdgcn_mfma_f32_16x16x32_bf16(a, b, acc[ct], 0, 0, 0);
        }
    }

#pragma unroll
    for (int ct = 0; ct < 4; ct++) {
        int j = 16 * ct + j0;
        float bz = bxz[j] + bhz[j];
        float br = bxr[j] + bhr[j];
        float bh = bxh[j];
#pragma unroll
        for (int reg = 0; reg < 4; reg++) {
            int r = r0 + q * 4 + reg;
            size_t i = (size_t)r * 64 + j;
            float zp = acc[ct][reg] + bz;
            float rp = acc[ct + 4][reg] + br;
            float hp = acc[ct + 8][reg] + bh;
            float zv = 1.f / (1.f + expf(-zp));
            float rv = 1.f / (1.f + expf(-rp));
            float hv = rv * ph[i];
            Zb[i] = zv;
            Hx[i] = hp;
            hr[i] = hv;
            A3[(size_t)r * 192 + j] = f2b(hv);
        }
    }
}

// ---------------- final GEMM (MFMA): [N,192]x[192,64] + GRU blend ----------------
__global__ __launch_bounds__(256) void k_final_mfma(
    const u16* __restrict__ A3, const u16* __restrict__ W3p,
    const float* __restrict__ bhh, const float* __restrict__ Hx,
    const float* __restrict__ Zb, const float* __restrict__ ph,
    float* __restrict__ outh) {
    int wv = (blockIdx.x * 256 + threadIdx.x) >> 6;
    int lane = threadIdx.x & 63;
    int r0 = wv * 16;
    if (r0 >= NN) return;
    int q = lane >> 4, j0 = lane & 15;

    f32x4 acc[4];
#pragma unroll
    for (int i = 0; i < 4; i++) acc[i] = (f32x4){0.f, 0.f, 0.f, 0.f};

    const u16* arow = A3 + (size_t)(r0 + j0) * 192 + q * 8;
#pragma unroll
    for (int s = 0; s < 6; s++) {
        bf16x8 a = *(const bf16x8*)(arow + 32 * s);
        const u16* bp = W3p + (size_t)(s * 4) * 512 + lane * 8;
#pragma unroll
        for (int ct = 0; ct < 4; ct++) {
            bf16x8 b = *(const bf16x8*)(bp + ct * 512);
            acc[ct] = __builtin_amdgcn_mfma_f32_16x16x32_bf16(a, b, acc[ct], 0, 0, 0);
        }
    }

#pragma unroll
    for (int ct = 0; ct < 4; ct++) {
        int j = 16 * ct + j0;
        float bh = bhh[j];
#pragma unroll
        for (int reg = 0; reg < 4; reg++) {
            int r = r0 + q * 4 + reg;
            size_t i = (size_t)r * 64 + j;
            float ht = tanhf(Hx[i] + acc[ct][reg] + bh);
            float zv = Zb[i];
            outh[i] = zv * ph[i] + (1.f - zv) * ht;
        }
    }
}

// ---------------- graph embedding (batch sorted -> run-accumulate) ----------------
__global__ void k_gemb(const float* __restrict__ z, const int* __restrict__ batch,
                       float* __restrict__ gemb) {
    int wave = (blockIdx.x * 256 + threadIdx.x) >> 6;
    int lane = threadIdx.x & 63;
    int n0 = wave * 64;
    if (n0 >= NN) return;
    int nend = n0 + 64 < NN ? n0 + 64 : NN;
    float acc = 0.f;
    int cur = batch[n0];
    for (int n = n0; n < nend; n++) {
        int b = batch[n];
        if (b != cur) {
            atomicAdd(&gemb[(size_t)cur * 64 + lane], acc);
            acc = 0.f;
            cur = b;
        }
        acc += z[(size_t)n * 64 + lane];
    }
    atomicAdd(&gemb[(size_t)cur * 64 + lane], acc);
}

__global__ __launch_bounds__(256) void k_fused(
    const float* __restrict__ u, const float* __restrict__ Wg, const float* __restrict__ bg,
    const float* __restrict__ gemb, float* __restrict__ out) {
    int t = blockIdx.x * 256 + threadIdx.x;
    int r = t >> 6, c = t & 63;
    if (r >= BB) return;
    float acc = bg[c];
    const float* ur = u + (size_t)r * 64;
    for (int k = 0; k < 64; k++) acc += ur[k] * Wg[k * 64 + c];
    acc = fmaxf(acc, 0.f);
    out[(size_t)r * 128 + c] = gemb[(size_t)r * 64 + c];
    out[(size_t)r * 128 + 64 + c] = acc;
}

extern "C" void kernel_launch(void* const* d_in, const int* in_sizes, int n_in,
                              void* d_out, int out_size, void* d_ws, size_t ws_size,
                              hipStream_t stream) {
    const float* x  = (const float*)d_in[0];
    const float* u  = (const float*)d_in[1];
    const float* z  = (const float*)d_in[2];
    const int*   ei = (const int*)d_in[3];
    const float* ew = (const float*)d_in[4];
    const int* batch = (const int*)d_in[5];
    const float* ph = (const float*)d_in[7];
    const float *Wxz = (const float*)d_in[8],  *bxz = (const float*)d_in[9];
    const float *Whz = (const float*)d_in[10], *bhz = (const float*)d_in[11];
    const float *Wxr = (const float*)d_in[12], *bxr = (const float*)d_in[13];
    const float *Whr = (const float*)d_in[14], *bhr = (const float*)d_in[15];
    const float *Wxh = (const float*)d_in[16], *bxh = (const float*)d_in[17];
    const float *Whh = (const float*)d_in[18], *bhh = (const float*)d_in[19];
    const float *Wg  = (const float*)d_in[20], *bg  = (const float*)d_in[21];
    const int* src = ei;
    const int* dst = ei + EE;

    char* wsb = (char*)d_ws;
    size_t o = 0;
    auto alloc = [&](size_t bytes) {
        void* p = wsb + o;
        o += (bytes + 255) & ~(size_t)255;
        return p;
    };
    float* deg     = (float*)alloc(NN * 4);      // becomes dinv in place
    int*   cnt     = (int*)alloc(NN * 4);
    int*   incl    = (int*)alloc(NN * 4);
    int*   row_ptr = (int*)alloc(NN * 4);
    int*   cursor  = (int*)alloc(NN * 4);
    int*   bsum    = (int*)alloc(256 * 4);
    int*   csr_src = (int*)alloc(EE * 4);
    float* csr_w   = (float*)alloc(EE * 4);
    float* xin  = (float*)alloc((size_t)NN * 96 * 4);
    float* t1x  = (float*)alloc((size_t)NN * 96 * 4);
    float* t1h  = (float*)alloc((size_t)NN * 64 * 4);
    float* hr   = (float*)alloc((size_t)NN * 64 * 4);
    float* t1hr = (float*)alloc((size_t)NN * 64 * 4);
    float* Zb   = (float*)alloc((size_t)NN * 64 * 4);
    float* Hx   = (float*)alloc((size_t)NN * 64 * 4);
    float* gemb = (float*)alloc((size_t)BB * 64 * 4);
    u16*   A    = (u16*)alloc((size_t)NN * 480 * 2);
    u16*   A3   = (u16*)alloc((size_t)NN * 192 * 2);
    u16*   Wp   = (u16*)alloc(15 * 12 * 512 * 2);
    u16*   W3p  = (u16*)alloc(6 * 4 * 512 * 2);

    float* outF = (float*)d_out;               // [B,128]
    float* outH = outF + (size_t)BB * 128;     // [N,64]

    const int BLK = 256;
    const int gE = (EE + BLK - 1) / BLK;
    const int gN = (NN + BLK - 1) / BLK;
    const int gN96 = (NN * 96 + BLK - 1) / BLK;
    const int gN64 = (NN * 64 + BLK - 1) / BLK;
    const int gPull64 = (NN + 15) / 16;   // 256 thr, 16 rows/blk
    const int gPull96 = (NN + 7) / 8;     // 192 thr, 8 rows/blk
    const int gMFMA = (3125 + 3) / 4;     // 3125 waves of 16 rows, 4 waves/blk

    // 1. degree / dinv
    hipMemsetAsync(deg, 0, NN * 4, stream);
    hipMemsetAsync(cnt, 0, NN * 4, stream);
    k_deg<<<gE, BLK, 0, stream>>>(src, ew, deg);
    k_dinv<<<gN, BLK, 0, stream>>>(deg);

    // 2. CSR by dst (norm folded into csr_w)
    k_indeg<<<gE, BLK, 0, stream>>>(dst, cnt);
    k_scan1<<<NB, 256, 0, stream>>>(cnt, incl, bsum);
    k_scan2<<<1, 256, 0, stream>>>(bsum);
    k_scan3<<<NB, 256, 0, stream>>>(incl, cnt, bsum, row_ptr, cursor);
    k_scatter<<<gE, BLK, 0, stream>>>(src, dst, ew, deg, cursor, csr_src, csr_w);

    // 3. pack weights, xin, ph slice
    k_packW<<<(15 * 12 * 512 + BLK - 1) / BLK, BLK, 0, stream>>>(Wxz, Wxr, Wxh, Whz, Whr, Wp);
    k_packW3<<<(6 * 4 * 512 + BLK - 1) / BLK, BLK, 0, stream>>>(Whh, W3p);
    k_build_xin<<<gN96, BLK, 0, stream>>>(z, x, xin, A);
    k_cvt_ph<<<gN64, BLK, 0, stream>>>(ph, A);

    // 4. Chebyshev bases (pull): t1 = -prop(t0); t2 = -2*prop(t1) - t0
    k_pull<96, 1, false, 192, true, true, 480><<<gPull96, 192, 0, stream>>>(
        xin, nullptr, t1x, A + 96, csr_src, csr_w, row_ptr, cnt);
    k_pull<96, 2, true, 192, false, true, 480><<<gPull96, 192, 0, stream>>>(
        t1x, xin, nullptr, A + 192, csr_src, csr_w, row_ptr, cnt);
    k_pull<64, 1, false, 256, true, true, 480><<<gPull64, 256, 0, stream>>>(
        ph, nullptr, t1h, A + 352, csr_src, csr_w, row_ptr, cnt);
    k_pull<64, 2, true, 256, false, true, 480><<<gPull64, 256, 0, stream>>>(
        t1h, ph, nullptr, A + 416, csr_src, csr_w, row_ptr, cnt);

    // 5. gates GEMM -> Z, hr (f32 + A3 slice), Hx
    k_gates_mfma<<<gMFMA, BLK, 0, stream>>>(A, Wp, bxz, bhz, bxr, bhr, bxh, ph,
                                            Zb, hr, Hx, A3);

    // 6. Chebyshev basis for hr
    k_pull<64, 1, false, 256, true, true, 192><<<gPull64, 256, 0, stream>>>(
        hr, nullptr, t1hr, A3 + 64, csr_src, csr_w, row_ptr, cnt);
    k_pull<64, 2, true, 256, false, true, 192><<<gPull64, 256, 0, stream>>>(
        t1hr, hr, nullptr, A3 + 128, csr_src, csr_w, row_ptr, cnt);

    // 7. candidate GEMM + GRU blend -> h out
    k_final_mfma<<<gMFMA, BLK, 0, stream>>>(A3, W3p, bhh, Hx, Zb, ph, outH);

    // 8. tail: graph emb + global emb -> fused out
    hipMemsetAsync(gemb, 0, (size_t)BB * 64 * 4, stream);
    k_gemb<<<gN, BLK, 0, stream>>>(z, batch, gemb);
    k_fused<<<(BB * 64 + BLK - 1) / BLK, BLK, 0, stream>>>(u, Wg, bg, gemb, outF);
}

// Round 5
// 480.772 us; speedup vs baseline: 11.8100x; 1.2777x over previous
//
#include <hip/hip_runtime.h>

#define NN 50000
#define EE 800000
#define BB 1000
#define NB 196  // ceil(NN/256)

typedef unsigned short u16;
typedef __attribute__((ext_vector_type(8))) short bf16x8;
typedef __attribute__((ext_vector_type(4))) float f32x4;

static __device__ __forceinline__ u16 f2b(float f) {
    union { float f; unsigned u; } v;
    v.f = f;
    unsigned r = v.u + 0x7fffu + ((v.u >> 16) & 1u);
    return (u16)(r >> 16);
}

static __device__ __forceinline__ float b2f(short s) {
    union { unsigned u; float f; } c;
    c.u = ((unsigned)(u16)s) << 16;
    return c.f;
}

// ---------------- fused degree(src) + indegree(dst) ----------------
__global__ void k_degcnt(const int* __restrict__ src, const int* __restrict__ dst,
                         const float* __restrict__ ew, float* __restrict__ deg,
                         int* __restrict__ cnt) {
    int e = blockIdx.x * 256 + threadIdx.x;
    if (e >= EE) return;
    atomicAdd(&deg[src[e]], ew[e]);
    atomicAdd(&cnt[dst[e]], 1);
}

// ---------------- CSR scan ----------------
__global__ void k_scan1(const int* __restrict__ cnt, int* __restrict__ incl,
                        int* __restrict__ bsum) {
    __shared__ int s[256];
    int i = blockIdx.x * 256 + threadIdx.x;
    int v = (i < NN) ? cnt[i] : 0;
    s[threadIdx.x] = v;
    __syncthreads();
    for (int off = 1; off < 256; off <<= 1) {
        int t = (threadIdx.x >= off) ? s[threadIdx.x - off] : 0;
        __syncthreads();
        s[threadIdx.x] += t;
        __syncthreads();
    }
    if (i < NN) incl[i] = s[threadIdx.x];
    if (threadIdx.x == 255) bsum[blockIdx.x] = s[255];
}

__global__ void k_scan2(int* __restrict__ bsum) {
    __shared__ int s[256];
    int v = (threadIdx.x < NB) ? bsum[threadIdx.x] : 0;
    s[threadIdx.x] = v;
    __syncthreads();
    for (int off = 1; off < 256; off <<= 1) {
        int t = (threadIdx.x >= off) ? s[threadIdx.x - off] : 0;
        __syncthreads();
        s[threadIdx.x] += t;
        __syncthreads();
    }
    if (threadIdx.x < NB) bsum[threadIdx.x] = s[threadIdx.x];
}

// scan3 + dinv fused
__global__ void k_scan3(const int* __restrict__ incl, const int* __restrict__ cnt,
                        const int* __restrict__ bsum, int* __restrict__ row_ptr,
                        int* __restrict__ cursor, float* __restrict__ deg) {
    int i = blockIdx.x * 256 + threadIdx.x;
    if (i >= NN) return;
    int off = (blockIdx.x > 0) ? bsum[blockIdx.x - 1] : 0;
    int start = off + incl[i] - cnt[i];
    row_ptr[i] = start;
    cursor[i] = start;
    float d = deg[i];
    deg[i] = d > 0.f ? rsqrtf(d) : 0.f;
}

// ---------------- scatter: 8B records {src, w} ----------------
__global__ void k_scatter(const int* __restrict__ src, const int* __restrict__ dst,
                          const float* __restrict__ ew, const float* __restrict__ dinv,
                          int* __restrict__ cursor, uint2* __restrict__ csr8) {
    int e = blockIdx.x * 256 + threadIdx.x;
    if (e >= EE) return;
    int d = dst[e], s = src[e];
    int pos = atomicAdd(&cursor[d], 1);
    float w = dinv[s] * ew[e] * dinv[d];
    csr8[pos] = make_uint2((unsigned)s, __float_as_uint(w));
}

// ---------------- build bf16 A slices: xin=[z|x] at 0, ph at 288 ----------------
__global__ void k_build_A(const float* __restrict__ z, const float* __restrict__ x,
                          const float* __restrict__ ph, u16* __restrict__ A) {
    int i = blockIdx.x * 256 + threadIdx.x;
    if (i >= NN * 160) return;
    int n = i / 160, c = i - n * 160;
    float v;
    int ofs;
    if (c < 64) {
        v = z[n * 64 + c];
        ofs = c;
    } else if (c < 96) {
        v = x[n * 32 + (c - 64)];
        ofs = c;
    } else {
        v = ph[n * 64 + (c - 96)];
        ofs = 288 + (c - 96);
    }
    A[(size_t)n * 480 + ofs] = f2b(v);
}

// ---------------- merged weight packing (Wp + W3p) ----------------
__global__ void k_packW_all(const float* __restrict__ Wxz, const float* __restrict__ Wxr,
                            const float* __restrict__ Wxh, const float* __restrict__ Whz,
                            const float* __restrict__ Whr, const float* __restrict__ Whh,
                            u16* __restrict__ Wp, u16* __restrict__ W3p) {
    int idx = blockIdx.x * 256 + threadIdx.x;
    if (idx < 15 * 12 * 512) {
        int j = idx & 7, l = (idx >> 3) & 63;
        int ct = (idx >> 9) % 12, s = (idx >> 9) / 12;
        int k = 32 * s + (l >> 4) * 8 + j;
        int g = ct >> 2;
        int c = 16 * (ct & 3) + (l & 15);
        float val;
        if (k < 288) {
            int ki = k / 96, kr = k - ki * 96;
            const float* W = (g == 0) ? Wxz : ((g == 1) ? Wxr : Wxh);
            val = W[(ki * 96 + kr) * 64 + c];
        } else if (g == 2) {
            val = 0.f;
        } else {
            int km = k - 288;
            int ki = km >> 6, kr = km & 63;
            const float* W = (g == 0) ? Whz : Whr;
            val = W[(ki * 64 + kr) * 64 + c];
        }
        Wp[idx] = f2b(val);
    } else {
        int i2 = idx - 15 * 12 * 512;
        if (i2 >= 6 * 4 * 512) return;
        int j = i2 & 7, l = (i2 >> 3) & 63;
        int ct = (i2 >> 9) & 3, s = i2 >> 11;
        int k = 32 * s + (l >> 4) * 8 + j;
        int ki = k >> 6, kr = k & 63;
        int c = 16 * ct + (l & 15);
        W3p[i2] = f2b(Whh[(ki * 64 + kr) * 64 + c]);
    }
}

// ---------------- bf16 pull propagation ----------------
// out_slice[r] = f2b( -SCALE * sum_e w_e * b2f(in_slice[src_e])  (HB: - base_slice[r]) )
// All slices live in one packed matrix Abase with row stride OS (elements).
template <int C, int SCALE, bool HB, int BS, int OS>
__global__ __launch_bounds__(BS) void k_pull(
    const u16* __restrict__ Abase, int inofs, int baseofs, int outofs,
    const uint2* __restrict__ csr8, const int* __restrict__ row_ptr,
    const int* __restrict__ cnt) {
    constexpr int TPR = C / 8;
    int tid = blockIdx.x * BS + threadIdx.x;
    int r = tid / TPR;
    int c8 = (tid - r * TPR) * 8;
    if (r >= NN) return;
    int s0 = row_ptr[r], n = cnt[r];
    float acc[8] = {0.f, 0.f, 0.f, 0.f, 0.f, 0.f, 0.f, 0.f};
    const u16* in = Abase + inofs + c8;
    uint2 e = (n > 0) ? csr8[s0] : make_uint2(0u, 0u);
    for (int j = 0; j < n; j++) {
        uint2 ec = e;
        if (j + 1 < n) e = csr8[s0 + j + 1];
        float w = __uint_as_float(ec.y);
        bf16x8 v = *(const bf16x8*)(in + (size_t)ec.x * OS);
#pragma unroll
        for (int k = 0; k < 8; k++) acc[k] += w * b2f(v[k]);
    }
    const float sc = -(float)SCALE;
    float o[8];
    if (HB) {
        bf16x8 b = *(const bf16x8*)(Abase + (size_t)r * OS + baseofs + c8);
#pragma unroll
        for (int k = 0; k < 8; k++) o[k] = sc * acc[k] - b2f(b[k]);
    } else {
#pragma unroll
        for (int k = 0; k < 8; k++) o[k] = sc * acc[k];
    }
    bf16x8 p;
#pragma unroll
    for (int k = 0; k < 8; k++) p[k] = (short)f2b(o[k]);
    *(bf16x8*)(const_cast<u16*>(Abase) + (size_t)r * OS + outofs + c8) = p;
}

// ---------------- gates GEMM (MFMA): [N,480]x[480,192] -> Z, Hx, A3 slice ----------------
__global__ __launch_bounds__(256) void k_gates_mfma(
    const u16* __restrict__ A, const u16* __restrict__ Wp,
    const float* __restrict__ bxz, const float* __restrict__ bhz,
    const float* __restrict__ bxr, const float* __restrict__ bhr,
    const float* __restrict__ bxh, const float* __restrict__ ph,
    float* __restrict__ Zb, float* __restrict__ Hx, u16* __restrict__ A3) {
    int wv = (blockIdx.x * 256 + threadIdx.x) >> 6;
    int lane = threadIdx.x & 63;
    int r0 = wv * 16;
    if (r0 >= NN) return;
    int q = lane >> 4, j0 = lane & 15;

    f32x4 acc[12];
#pragma unroll
    for (int i = 0; i < 12; i++) acc[i] = (f32x4){0.f, 0.f, 0.f, 0.f};

    const u16* arow = A + (size_t)(r0 + j0) * 480 + q * 8;
#pragma unroll
    for (int s = 0; s < 15; s++) {
        bf16x8 a = *(const bf16x8*)(arow + 32 * s);
        const u16* bp = Wp + (size_t)(s * 12) * 512 + lane * 8;
#pragma unroll
        for (int ct = 0; ct < 12; ct++) {
            bf16x8 b = *(const bf16x8*)(bp + ct * 512);
            acc[ct] = __builtin_amdgcn_mfma_f32_16x16x32_bf16(a, b, acc[ct], 0, 0, 0);
        }
    }

#pragma unroll
    for (int ct = 0; ct < 4; ct++) {
        int j = 16 * ct + j0;
        float bz = bxz[j] + bhz[j];
        float br = bxr[j] + bhr[j];
        float bh = bxh[j];
#pragma unroll
        for (int reg = 0; reg < 4; reg++) {
            int r = r0 + q * 4 + reg;
            size_t i = (size_t)r * 64 + j;
            float zp = acc[ct][reg] + bz;
            float rp = acc[ct + 4][reg] + br;
            float hp = acc[ct + 8][reg] + bh;
            float zv = 1.f / (1.f + expf(-zp));
            float rv = 1.f / (1.f + expf(-rp));
            float hv = rv * ph[i];
            Zb[i] = zv;
            Hx[i] = hp;
            A3[(size_t)r * 192 + j] = f2b(hv);
        }
    }
}

// ---------------- final GEMM (MFMA): [N,192]x[192,64] + GRU blend ----------------
__global__ __launch_bounds__(256) void k_final_mfma(
    const u16* __restrict__ A3, const u16* __restrict__ W3p,
    const float* __restrict__ bhh, const float* __restrict__ Hx,
    const float* __restrict__ Zb, const float* __restrict__ ph,
    float* __restrict__ outh) {
    int wv = (blockIdx.x * 256 + threadIdx.x) >> 6;
    int lane = threadIdx.x & 63;
    int r0 = wv * 16;
    if (r0 >= NN) return;
    int q = lane >> 4, j0 = lane & 15;

    f32x4 acc[4];
#pragma unroll
    for (int i = 0; i < 4; i++) acc[i] = (f32x4){0.f, 0.f, 0.f, 0.f};

    const u16* arow = A3 + (size_t)(r0 + j0) * 192 + q * 8;
#pragma unroll
    for (int s = 0; s < 6; s++) {
        bf16x8 a = *(const bf16x8*)(arow + 32 * s);
        const u16* bp = W3p + (size_t)(s * 4) * 512 + lane * 8;
#pragma unroll
        for (int ct = 0; ct < 4; ct++) {
            bf16x8 b = *(const bf16x8*)(bp + ct * 512);
            acc[ct] = __builtin_amdgcn_mfma_f32_16x16x32_bf16(a, b, acc[ct], 0, 0, 0);
        }
    }

#pragma unroll
    for (int ct = 0; ct < 4; ct++) {
        int j = 16 * ct + j0;
        float bh = bhh[j];
#pragma unroll
        for (int reg = 0; reg < 4; reg++) {
            int r = r0 + q * 4 + reg;
            size_t i = (size_t)r * 64 + j;
            float ht = tanhf(Hx[i] + acc[ct][reg] + bh);
            float zv = Zb[i];
            outh[i] = zv * ph[i] + (1.f - zv) * ht;
        }
    }
}

// ---------------- graph embedding (batch sorted -> run-accumulate) ----------------
__global__ void k_gemb(const float* __restrict__ z, const int* __restrict__ batch,
                       float* __restrict__ gemb) {
    int wave = (blockIdx.x * 256 + threadIdx.x) >> 6;
    int lane = threadIdx.x & 63;
    int n0 = wave * 64;
    if (n0 >= NN) return;
    int nend = n0 + 64 < NN ? n0 + 64 : NN;
    float acc = 0.f;
    int cur = batch[n0];
    for (int n = n0; n < nend; n++) {
        int b = batch[n];
        if (b != cur) {
            atomicAdd(&gemb[(size_t)cur * 64 + lane], acc);
            acc = 0.f;
            cur = b;
        }
        acc += z[(size_t)n * 64 + lane];
    }
    atomicAdd(&gemb[(size_t)cur * 64 + lane], acc);
}

__global__ __launch_bounds__(256) void k_fused(
    const float* __restrict__ u, const float* __restrict__ Wg, const float* __restrict__ bg,
    const float* __restrict__ gemb, float* __restrict__ out) {
    int t = blockIdx.x * 256 + threadIdx.x;
    int r = t >> 6, c = t & 63;
    if (r >= BB) return;
    float acc = bg[c];
    const float* ur = u + (size_t)r * 64;
    for (int k = 0; k < 64; k++) acc += ur[k] * Wg[k * 64 + c];
    acc = fmaxf(acc, 0.f);
    out[(size_t)r * 128 + c] = gemb[(size_t)r * 64 + c];
    out[(size_t)r * 128 + 64 + c] = acc;
}

extern "C" void kernel_launch(void* const* d_in, const int* in_sizes, int n_in,
                              void* d_out, int out_size, void* d_ws, size_t ws_size,
                              hipStream_t stream) {
    const float* x  = (const float*)d_in[0];
    const float* u  = (const float*)d_in[1];
    const float* z  = (const float*)d_in[2];
    const int*   ei = (const int*)d_in[3];
    const float* ew = (const float*)d_in[4];
    const int* batch = (const int*)d_in[5];
    const float* ph = (const float*)d_in[7];
    const float *Wxz = (const float*)d_in[8],  *bxz = (const float*)d_in[9];
    const float *Whz = (const float*)d_in[10], *bhz = (const float*)d_in[11];
    const float *Wxr = (const float*)d_in[12], *bxr = (const float*)d_in[13];
    const float *Whr = (const float*)d_in[14], *bhr = (const float*)d_in[15];
    const float *Wxh = (const float*)d_in[16], *bxh = (const float*)d_in[17];
    const float *Whh = (const float*)d_in[18], *bhh = (const float*)d_in[19];
    const float *Wg  = (const float*)d_in[20], *bg  = (const float*)d_in[21];
    const int* src = ei;
    const int* dst = ei + EE;

    char* wsb = (char*)d_ws;
    size_t o = 0;
    auto alloc = [&](size_t bytes) {
        void* p = wsb + o;
        o += (bytes + 255) & ~(size_t)255;
        return p;
    };
    int*   degcnt  = (int*)alloc(2 * NN * 4);   // [deg | cnt] — one memset
    float* deg     = (float*)degcnt;            // becomes dinv in scan3
    int*   cnt     = degcnt + NN;
    int*   incl    = (int*)alloc(NN * 4);
    int*   row_ptr = (int*)alloc(NN * 4);
    int*   cursor  = (int*)alloc(NN * 4);
    int*   bsum    = (int*)alloc(256 * 4);
    uint2* csr8    = (uint2*)alloc((size_t)EE * 8);
    float* Zb   = (float*)alloc((size_t)NN * 64 * 4);
    float* Hx   = (float*)alloc((size_t)NN * 64 * 4);
    float* gemb = (float*)alloc((size_t)BB * 64 * 4);
    u16*   A    = (u16*)alloc((size_t)NN * 480 * 2);
    u16*   A3   = (u16*)alloc((size_t)NN * 192 * 2);
    u16*   Wp   = (u16*)alloc(15 * 12 * 512 * 2);
    u16*   W3p  = (u16*)alloc(6 * 4 * 512 * 2);

    float* outF = (float*)d_out;               // [B,128]
    float* outH = outF + (size_t)BB * 128;     // [N,64]

    const int BLK = 256;
    const int gE = (EE + BLK - 1) / BLK;
    const int gA = (NN * 160 + BLK - 1) / BLK;
    const int gPull96 = (NN + 15) / 16;   // 192 thr, 12 thr/row -> 16 rows/blk
    const int gPull64 = (NN + 31) / 32;   // 256 thr, 8 thr/row -> 32 rows/blk
    const int gMFMA = (3125 + 3) / 4;
    const int gPack = (15 * 12 * 512 + 6 * 4 * 512 + BLK - 1) / BLK;

    // 1. degree + indegree (one edge pass)
    hipMemsetAsync(degcnt, 0, 2 * NN * 4, stream);
    k_degcnt<<<gE, BLK, 0, stream>>>(src, dst, ew, deg, cnt);

    // 2. CSR scan (+ dinv in scan3), scatter 8B records
    k_scan1<<<NB, 256, 0, stream>>>(cnt, incl, bsum);
    k_scan2<<<1, 256, 0, stream>>>(bsum);
    k_scan3<<<NB, 256, 0, stream>>>(incl, cnt, bsum, row_ptr, cursor, deg);
    k_scatter<<<gE, BLK, 0, stream>>>(src, dst, ew, deg, cursor, csr8);

    // 3. pack weights + build A (xin, ph slices)
    k_packW_all<<<gPack, BLK, 0, stream>>>(Wxz, Wxr, Wxh, Whz, Whr, Whh, Wp, W3p);
    k_build_A<<<gA, BLK, 0, stream>>>(z, x, ph, A);

    // 4. Chebyshev bases (bf16 pull): t1 = -prop(t0); t2 = -2*prop(t1) - t0
    k_pull<96, 1, false, 192, 480><<<gPull96, 192, 0, stream>>>(A, 0, 0, 96, csr8, row_ptr, cnt);
    k_pull<96, 2, true, 192, 480><<<gPull96, 192, 0, stream>>>(A, 96, 0, 192, csr8, row_ptr, cnt);
    k_pull<64, 1, false, 256, 480><<<gPull64, 256, 0, stream>>>(A, 288, 0, 352, csr8, row_ptr, cnt);
    k_pull<64, 2, true, 256, 480><<<gPull64, 256, 0, stream>>>(A, 352, 288, 416, csr8, row_ptr, cnt);

    // 5. gates GEMM -> Z, Hx, A3 slice 0 (hr)
    k_gates_mfma<<<gMFMA, BLK, 0, stream>>>(A, Wp, bxz, bhz, bxr, bhr, bxh, ph, Zb, Hx, A3);

    // 6. Chebyshev basis for hr (in A3)
    k_pull<64, 1, false, 256, 192><<<gPull64, 256, 0, stream>>>(A3, 0, 0, 64, csr8, row_ptr, cnt);
    k_pull<64, 2, true, 256, 192><<<gPull64, 256, 0, stream>>>(A3, 64, 0, 128, csr8, row_ptr, cnt);

    // 7. candidate GEMM + GRU blend -> h out
    k_final_mfma<<<gMFMA, BLK, 0, stream>>>(A3, W3p, bhh, Hx, Zb, ph, outH);

    // 8. tail: graph emb + global emb -> fused out
    hipMemsetAsync(gemb, 0, (size_t)BB * 64 * 4, stream);
    k_gemb<<<(NN + BLK - 1) / BLK, BLK, 0, stream>>>(z, batch, gemb);
    k_fused<<<(BB * 64 + BLK - 1) / BLK, BLK, 0, stream>>>(u, Wg, bg, gemb, outF);
}

// Round 6
// 455.456 us; speedup vs baseline: 12.4665x; 1.0556x over previous
//
#include <hip/hip_runtime.h>

#define NN 50000
#define EE 800000
#define BB 1000
#define NB 196  // ceil(NN/256)
#define NCOPY 8

typedef unsigned short u16;
typedef __attribute__((ext_vector_type(8))) short bf16x8;
typedef __attribute__((ext_vector_type(4))) float f32x4;

static __device__ __forceinline__ u16 f2b(float f) {
    union { float f; unsigned u; } v;
    v.f = f;
    unsigned r = v.u + 0x7fffu + ((v.u >> 16) & 1u);
    return (u16)(r >> 16);
}

static __device__ __forceinline__ float b2f(short s) {
    union { unsigned u; float f; } c;
    c.u = ((unsigned)(u16)s) << 16;
    return c.f;
}

// ---------------- degree(src) + indegree(dst), 8-way partial histograms ----------------
__global__ void k_degcnt(const int* __restrict__ src, const int* __restrict__ dst,
                         const float* __restrict__ ew, float* __restrict__ deg_p,
                         int* __restrict__ cnt_p) {
    int e = blockIdx.x * 256 + threadIdx.x;
    if (e >= EE) return;
    int cp = blockIdx.x & (NCOPY - 1);   // matches round-robin block->XCD
    atomicAdd(&deg_p[(size_t)cp * NN + src[e]], ew[e]);
    atomicAdd(&cnt_p[(size_t)cp * NN + dst[e]], 1);
}

// ---------------- CSR scan (scan1 reduces cnt copies) ----------------
__global__ void k_scan1(const int* __restrict__ cnt_p, int* __restrict__ cnt,
                        int* __restrict__ incl, int* __restrict__ bsum) {
    __shared__ int s[256];
    int i = blockIdx.x * 256 + threadIdx.x;
    int v = 0;
    if (i < NN) {
#pragma unroll
        for (int p = 0; p < NCOPY; p++) v += cnt_p[(size_t)p * NN + i];
        cnt[i] = v;
    }
    s[threadIdx.x] = v;
    __syncthreads();
    for (int off = 1; off < 256; off <<= 1) {
        int t = (threadIdx.x >= off) ? s[threadIdx.x - off] : 0;
        __syncthreads();
        s[threadIdx.x] += t;
        __syncthreads();
    }
    if (i < NN) incl[i] = s[threadIdx.x];
    if (threadIdx.x == 255) bsum[blockIdx.x] = s[255];
}

__global__ void k_scan2(int* __restrict__ bsum) {
    __shared__ int s[256];
    int v = (threadIdx.x < NB) ? bsum[threadIdx.x] : 0;
    s[threadIdx.x] = v;
    __syncthreads();
    for (int off = 1; off < 256; off <<= 1) {
        int t = (threadIdx.x >= off) ? s[threadIdx.x - off] : 0;
        __syncthreads();
        s[threadIdx.x] += t;
        __syncthreads();
    }
    if (threadIdx.x < NB) bsum[threadIdx.x] = s[threadIdx.x];
}

// scan3: row_ptr/cursor + dinv (reduces deg copies)
__global__ void k_scan3(const int* __restrict__ incl, const int* __restrict__ cnt,
                        const int* __restrict__ bsum, int* __restrict__ row_ptr,
                        int* __restrict__ cursor, const float* __restrict__ deg_p,
                        float* __restrict__ dinv) {
    int i = blockIdx.x * 256 + threadIdx.x;
    if (i >= NN) return;
    int off = (blockIdx.x > 0) ? bsum[blockIdx.x - 1] : 0;
    int start = off + incl[i] - cnt[i];
    row_ptr[i] = start;
    cursor[i] = start;
    float d = 0.f;
#pragma unroll
    for (int p = 0; p < NCOPY; p++) d += deg_p[(size_t)p * NN + i];
    dinv[i] = d > 0.f ? rsqrtf(d) : 0.f;
}

// ---------------- scatter: 8B records {src, w} ----------------
__global__ void k_scatter(const int* __restrict__ src, const int* __restrict__ dst,
                          const float* __restrict__ ew, const float* __restrict__ dinv,
                          int* __restrict__ cursor, uint2* __restrict__ csr8) {
    int e = blockIdx.x * 256 + threadIdx.x;
    if (e >= EE) return;
    int d = dst[e], s = src[e];
    int pos = atomicAdd(&cursor[d], 1);
    float w = dinv[s] * ew[e] * dinv[d];
    csr8[pos] = make_uint2((unsigned)s, __float_as_uint(w));
}

// ---------------- build bf16 A level-0 slice: [z | x | ph] at 0..160 ----------------
__global__ void k_build_A(const float* __restrict__ z, const float* __restrict__ x,
                          const float* __restrict__ ph, u16* __restrict__ A) {
    int i = blockIdx.x * 256 + threadIdx.x;
    if (i >= NN * 160) return;
    int n = i / 160, c = i - n * 160;
    float v;
    if (c < 64) v = z[n * 64 + c];
    else if (c < 96) v = x[n * 32 + (c - 64)];
    else v = ph[n * 64 + (c - 96)];
    A[(size_t)n * 480 + c] = f2b(v);
}

// ---------------- merged weight packing (Wp + W3p) ----------------
// A k-layout: [xin(0:96)|ph(96:160)|t1x(160:256)|t1h(256:320)|t2x(320:416)|t2h(416:480)]
__global__ void k_packW_all(const float* __restrict__ Wxz, const float* __restrict__ Wxr,
                            const float* __restrict__ Wxh, const float* __restrict__ Whz,
                            const float* __restrict__ Whr, const float* __restrict__ Whh,
                            u16* __restrict__ Wp, u16* __restrict__ W3p) {
    int idx = blockIdx.x * 256 + threadIdx.x;
    if (idx < 15 * 12 * 512) {
        int j = idx & 7, l = (idx >> 3) & 63;
        int ct = (idx >> 9) % 12, s = (idx >> 9) / 12;
        int k = 32 * s + (l >> 4) * 8 + j;
        int g = ct >> 2;
        int c = 16 * (ct & 3) + (l & 15);
        bool isX;
        int kr;
        if (k < 96)       { isX = true;  kr = k; }
        else if (k < 160) { isX = false; kr = k - 96; }
        else if (k < 256) { isX = true;  kr = 96 + (k - 160); }
        else if (k < 320) { isX = false; kr = 64 + (k - 256); }
        else if (k < 416) { isX = true;  kr = 192 + (k - 320); }
        else              { isX = false; kr = 128 + (k - 416); }
        float val;
        if (isX) {
            const float* W = (g == 0) ? Wxz : ((g == 1) ? Wxr : Wxh);
            val = W[kr * 64 + c];
        } else if (g == 2) {
            val = 0.f;
        } else {
            const float* W = (g == 0) ? Whz : Whr;
            val = W[kr * 64 + c];
        }
        Wp[idx] = f2b(val);
    } else {
        int i2 = idx - 15 * 12 * 512;
        if (i2 >= 6 * 4 * 512) return;
        int j = i2 & 7, l = (i2 >> 3) & 63;
        int ct = (i2 >> 9) & 3, s = i2 >> 11;
        int k = 32 * s + (l >> 4) * 8 + j;
        int ki = k >> 6, kr = k & 63;
        int c = 16 * ct + (l & 15);
        W3p[i2] = f2b(Whh[(ki * 64 + kr) * 64 + c]);
    }
}

// ---------------- bf16 pull propagation ----------------
// out_slice[r] = f2b( -SCALE * sum_e w_e * b2f(in_slice[src_e])  (HB: - base_slice[r]) )
template <int C, int SCALE, bool HB, int BS, int OS>
__global__ __launch_bounds__(BS) void k_pull(
    const u16* __restrict__ Abase, int inofs, int baseofs, int outofs,
    const uint2* __restrict__ csr8, const int* __restrict__ row_ptr,
    const int* __restrict__ cnt) {
    constexpr int TPR = C / 8;
    int tid = blockIdx.x * BS + threadIdx.x;
    int r = tid / TPR;
    int c8 = (tid - r * TPR) * 8;
    if (r >= NN) return;
    int s0 = row_ptr[r], n = cnt[r];
    float acc[8] = {0.f, 0.f, 0.f, 0.f, 0.f, 0.f, 0.f, 0.f};
    const u16* in = Abase + inofs + c8;
    uint2 e = (n > 0) ? csr8[s0] : make_uint2(0u, 0u);
    for (int j = 0; j < n; j++) {
        uint2 ec = e;
        if (j + 1 < n) e = csr8[s0 + j + 1];
        float w = __uint_as_float(ec.y);
        bf16x8 v = *(const bf16x8*)(in + (size_t)ec.x * OS);
#pragma unroll
        for (int k = 0; k < 8; k++) acc[k] += w * b2f(v[k]);
    }
    const float sc = -(float)SCALE;
    float o[8];
    if (HB) {
        bf16x8 b = *(const bf16x8*)(Abase + (size_t)r * OS + baseofs + c8);
#pragma unroll
        for (int k = 0; k < 8; k++) o[k] = sc * acc[k] - b2f(b[k]);
    } else {
#pragma unroll
        for (int k = 0; k < 8; k++) o[k] = sc * acc[k];
    }
    bf16x8 p;
#pragma unroll
    for (int k = 0; k < 8; k++) p[k] = (short)f2b(o[k]);
    *(bf16x8*)(const_cast<u16*>(Abase) + (size_t)r * OS + outofs + c8) = p;
}

// ---------------- gates GEMM (MFMA): [N,480]x[480,192] -> Zb16, Hx16, A3 slice ----------------
__global__ __launch_bounds__(256) void k_gates_mfma(
    const u16* __restrict__ A, const u16* __restrict__ Wp,
    const float* __restrict__ bxz, const float* __restrict__ bhz,
    const float* __restrict__ bxr, const float* __restrict__ bhr,
    const float* __restrict__ bxh,
    u16* __restrict__ Zb16, u16* __restrict__ Hx16, u16* __restrict__ A3) {
    int wv = (blockIdx.x * 256 + threadIdx.x) >> 6;
    int lane = threadIdx.x & 63;
    int r0 = wv * 16;
    if (r0 >= NN) return;
    int q = lane >> 4, j0 = lane & 15;

    f32x4 acc[12];
#pragma unroll
    for (int i = 0; i < 12; i++) acc[i] = (f32x4){0.f, 0.f, 0.f, 0.f};

    const u16* arow = A + (size_t)(r0 + j0) * 480 + q * 8;
#pragma unroll
    for (int s = 0; s < 15; s++) {
        bf16x8 a = *(const bf16x8*)(arow + 32 * s);
        const u16* bp = Wp + (size_t)(s * 12) * 512 + lane * 8;
#pragma unroll
        for (int ct = 0; ct < 12; ct++) {
            bf16x8 b = *(const bf16x8*)(bp + ct * 512);
            acc[ct] = __builtin_amdgcn_mfma_f32_16x16x32_bf16(a, b, acc[ct], 0, 0, 0);
        }
    }

#pragma unroll
    for (int ct = 0; ct < 4; ct++) {
        int j = 16 * ct + j0;
        float bz = bxz[j] + bhz[j];
        float br = bxr[j] + bhr[j];
        float bh = bxh[j];
#pragma unroll
        for (int reg = 0; reg < 4; reg++) {
            int r = r0 + q * 4 + reg;
            size_t i = (size_t)r * 64 + j;
            float zp = acc[ct][reg] + bz;
            float rp = acc[ct + 4][reg] + br;
            float hp = acc[ct + 8][reg] + bh;
            float zv = 1.f / (1.f + expf(-zp));
            float rv = 1.f / (1.f + expf(-rp));
            float phv = b2f((short)A[(size_t)r * 480 + 96 + j]);
            Zb16[i] = f2b(zv);
            Hx16[i] = f2b(hp);
            A3[(size_t)r * 192 + j] = f2b(rv * phv);
        }
    }
}

// ---------------- final GEMM (MFMA): [N,192]x[192,64] + GRU blend ----------------
__global__ __launch_bounds__(256) void k_final_mfma(
    const u16* __restrict__ A3, const u16* __restrict__ W3p,
    const float* __restrict__ bhh, const u16* __restrict__ Hx16,
    const u16* __restrict__ Zb16, const u16* __restrict__ A,
    float* __restrict__ outh) {
    int wv = (blockIdx.x * 256 + threadIdx.x) >> 6;
    int lane = threadIdx.x & 63;
    int r0 = wv * 16;
    if (r0 >= NN) return;
    int q = lane >> 4, j0 = lane & 15;

    f32x4 acc[4];
#pragma unroll
    for (int i = 0; i < 4; i++) acc[i] = (f32x4){0.f, 0.f, 0.f, 0.f};

    const u16* arow = A3 + (size_t)(r0 + j0) * 192 + q * 8;
#pragma unroll
    for (int s = 0; s < 6; s++) {
        bf16x8 a = *(const bf16x8*)(arow + 32 * s);
        const u16* bp = W3p + (size_t)(s * 4) * 512 + lane * 8;
#pragma unroll
        for (int ct = 0; ct < 4; ct++) {
            bf16x8 b = *(const bf16x8*)(bp + ct * 512);
            acc[ct] = __builtin_amdgcn_mfma_f32_16x16x32_bf16(a, b, acc[ct], 0, 0, 0);
        }
    }

#pragma unroll
    for (int ct = 0; ct < 4; ct++) {
        int j = 16 * ct + j0;
        float bh = bhh[j];
#pragma unroll
        for (int reg = 0; reg < 4; reg++) {
            int r = r0 + q * 4 + reg;
            size_t i = (size_t)r * 64 + j;
            float ht = tanhf(b2f((short)Hx16[i]) + acc[ct][reg] + bh);
            float zv = b2f((short)Zb16[i]);
            float phv = b2f((short)A[(size_t)r * 480 + 96 + j]);
            outh[i] = zv * phv + (1.f - zv) * ht;
        }
    }
}

// ---------------- graph embedding (batch sorted -> run-accumulate) ----------------
__global__ void k_gemb(const float* __restrict__ z, const int* __restrict__ batch,
                       float* __restrict__ gemb) {
    int wave = (blockIdx.x * 256 + threadIdx.x) >> 6;
    int lane = threadIdx.x & 63;
    int n0 = wave * 64;
    if (n0 >= NN) return;
    int nend = n0 + 64 < NN ? n0 + 64 : NN;
    float acc = 0.f;
    int cur = batch[n0];
    for (int n = n0; n < nend; n++) {
        int b = batch[n];
        if (b != cur) {
            atomicAdd(&gemb[(size_t)cur * 64 + lane], acc);
            acc = 0.f;
            cur = b;
        }
        acc += z[(size_t)n * 64 + lane];
    }
    atomicAdd(&gemb[(size_t)cur * 64 + lane], acc);
}

__global__ __launch_bounds__(256) void k_fused(
    const float* __restrict__ u, const float* __restrict__ Wg, const float* __restrict__ bg,
    const float* __restrict__ gemb, float* __restrict__ out) {
    int t = blockIdx.x * 256 + threadIdx.x;
    int r = t >> 6, c = t & 63;
    if (r >= BB) return;
    float acc = bg[c];
    const float* ur = u + (size_t)r * 64;
    for (int k = 0; k < 64; k++) acc += ur[k] * Wg[k * 64 + c];
    acc = fmaxf(acc, 0.f);
    out[(size_t)r * 128 + c] = gemb[(size_t)r * 64 + c];
    out[(size_t)r * 128 + 64 + c] = acc;
}

extern "C" void kernel_launch(void* const* d_in, const int* in_sizes, int n_in,
                              void* d_out, int out_size, void* d_ws, size_t ws_size,
                              hipStream_t stream) {
    const float* x  = (const float*)d_in[0];
    const float* u  = (const float*)d_in[1];
    const float* z  = (const float*)d_in[2];
    const int*   ei = (const int*)d_in[3];
    const float* ew = (const float*)d_in[4];
    const int* batch = (const int*)d_in[5];
    const float* ph = (const float*)d_in[7];
    const float *Wxz = (const float*)d_in[8],  *bxz = (const float*)d_in[9];
    const float *Whz = (const float*)d_in[10], *bhz = (const float*)d_in[11];
    const float *Wxr = (const float*)d_in[12], *bxr = (const float*)d_in[13];
    const float *Whr = (const float*)d_in[14], *bhr = (const float*)d_in[15];
    const float *Wxh = (const float*)d_in[16], *bxh = (const float*)d_in[17];
    const float *Whh = (const float*)d_in[18], *bhh = (const float*)d_in[19];
    const float *Wg  = (const float*)d_in[20], *bg  = (const float*)d_in[21];
    const int* src = ei;
    const int* dst = ei + EE;

    char* wsb = (char*)d_ws;
    size_t o = 0;
    auto alloc = [&](size_t bytes) {
        void* p = wsb + o;
        o += (bytes + 255) & ~(size_t)255;
        return p;
    };
    float* deg_p   = (float*)alloc((size_t)NCOPY * NN * 4);  // \ one memset
    int*   cnt_p   = (int*)alloc((size_t)NCOPY * NN * 4);    // /
    int*   cnt     = (int*)alloc(NN * 4);
    int*   incl    = (int*)alloc(NN * 4);
    int*   row_ptr = (int*)alloc(NN * 4);
    int*   cursor  = (int*)alloc(NN * 4);
    float* dinv    = (float*)alloc(NN * 4);
    int*   bsum    = (int*)alloc(256 * 4);
    uint2* csr8    = (uint2*)alloc((size_t)EE * 8);
    u16*   Zb16 = (u16*)alloc((size_t)NN * 64 * 2);
    u16*   Hx16 = (u16*)alloc((size_t)NN * 64 * 2);
    float* gemb = (float*)alloc((size_t)BB * 64 * 4);
    u16*   A    = (u16*)alloc((size_t)NN * 480 * 2);
    u16*   A3   = (u16*)alloc((size_t)NN * 192 * 2);
    u16*   Wp   = (u16*)alloc(15 * 12 * 512 * 2);
    u16*   W3p  = (u16*)alloc(6 * 4 * 512 * 2);

    float* outF = (float*)d_out;               // [B,128]
    float* outH = outF + (size_t)BB * 128;     // [N,64]

    const int BLK = 256;
    const int gE = (EE + BLK - 1) / BLK;
    const int gA = (NN * 160 + BLK - 1) / BLK;
    const int gPull160 = (NN + 15) / 16;  // 320 thr, 20 thr/row -> 16 rows/blk
    const int gPull64 = (NN + 31) / 32;   // 256 thr, 8 thr/row -> 32 rows/blk
    const int gMFMA = (3125 + 3) / 4;
    const int gPack = (15 * 12 * 512 + 6 * 4 * 512 + BLK - 1) / BLK;

    // 0. independent prep
    k_packW_all<<<gPack, BLK, 0, stream>>>(Wxz, Wxr, Wxh, Whz, Whr, Whh, Wp, W3p);
    k_build_A<<<gA, BLK, 0, stream>>>(z, x, ph, A);

    // 1. degree + indegree partial histograms (one edge pass)
    hipMemsetAsync(deg_p, 0, (size_t)2 * NCOPY * NN * 4, stream);
    k_degcnt<<<gE, BLK, 0, stream>>>(src, dst, ew, deg_p, cnt_p);

    // 2. CSR scan (reduce copies; dinv in scan3), scatter 8B records
    k_scan1<<<NB, 256, 0, stream>>>(cnt_p, cnt, incl, bsum);
    k_scan2<<<1, 256, 0, stream>>>(bsum);
    k_scan3<<<NB, 256, 0, stream>>>(incl, cnt, bsum, row_ptr, cursor, deg_p, dinv);
    k_scatter<<<gE, BLK, 0, stream>>>(src, dst, ew, dinv, cursor, csr8);

    // 3. Chebyshev bases, merged 160-ch pulls: t1 = -prop(t0); t2 = -2*prop(t1) - t0
    k_pull<160, 1, false, 320, 480><<<gPull160, 320, 0, stream>>>(A, 0, 0, 160, csr8, row_ptr, cnt);
    k_pull<160, 2, true, 320, 480><<<gPull160, 320, 0, stream>>>(A, 160, 0, 320, csr8, row_ptr, cnt);

    // 4. gates GEMM -> Zb16, Hx16, A3 slice 0 (hr)
    k_gates_mfma<<<gMFMA, BLK, 0, stream>>>(A, Wp, bxz, bhz, bxr, bhr, bxh, Zb16, Hx16, A3);

    // 5. Chebyshev basis for hr (in A3)
    k_pull<64, 1, false, 256, 192><<<gPull64, 256, 0, stream>>>(A3, 0, 0, 64, csr8, row_ptr, cnt);
    k_pull<64, 2, true, 256, 192><<<gPull64, 256, 0, stream>>>(A3, 64, 0, 128, csr8, row_ptr, cnt);

    // 6. candidate GEMM + GRU blend -> h out
    k_final_mfma<<<gMFMA, BLK, 0, stream>>>(A3, W3p, bhh, Hx16, Zb16, A, outH);

    // 7. tail: graph emb + global emb -> fused out
    hipMemsetAsync(gemb, 0, (size_t)BB * 64 * 4, stream);
    k_gemb<<<(NN + BLK - 1) / BLK, BLK, 0, stream>>>(z, batch, gemb);
    k_fused<<<(BB * 64 + BLK - 1) / BLK, BLK, 0, stream>>>(u, Wg, bg, gemb, outF);
}

// Round 7
// 425.657 us; speedup vs baseline: 13.3392x; 1.0700x over previous
//
#include <hip/hip_runtime.h>

#define NN 50000
#define EE 800000
#define BB 1000
#define NB 196  // ceil(NN/256)
#define NR 8        // node ranges for LDS histogram
#define RS 6272     // range size, NR*RS = 50176 >= NN
#define NC 32       // edge chunks / partial copies
#define CHUNK 25000 // EE/NC

typedef unsigned short u16;
typedef __attribute__((ext_vector_type(8))) short bf16x8;
typedef __attribute__((ext_vector_type(4))) float f32x4;

static __device__ __forceinline__ u16 f2b(float f) {
    union { float f; unsigned u; } v;
    v.f = f;
    unsigned r = v.u + 0x7fffu + ((v.u >> 16) & 1u);
    return (u16)(r >> 16);
}

static __device__ __forceinline__ float b2f(short s) {
    union { unsigned u; float f; } c;
    c.u = ((unsigned)(u16)s) << 16;
    return c.f;
}

// ---------------- degree(src)+indegree(dst): LDS-privatized, zero global atomics ----------------
// block (r = bid&7, c = bid>>3): range r of nodes, chunk c of edges.
__global__ __launch_bounds__(512) void k_degcnt_lds(
    const int* __restrict__ src, const int* __restrict__ dst,
    const float* __restrict__ ew, float* __restrict__ deg_p,
    int* __restrict__ cnt_p) {
    __shared__ float sdeg[RS];
    __shared__ int scnt[RS];
    int r = blockIdx.x & (NR - 1);
    int c = blockIdx.x >> 3;
    int base = r * RS;
    for (int i = threadIdx.x; i < RS; i += 512) {
        sdeg[i] = 0.f;
        scnt[i] = 0;
    }
    __syncthreads();
    int e0 = c * CHUNK;
    for (int j = threadIdx.x; j < CHUNK; j += 512) {
        int e = e0 + j;
        int s = src[e], d = dst[e];
        int sl = s - base, dl = d - base;
        if ((unsigned)sl < RS) atomicAdd(&sdeg[sl], ew[e]);
        if ((unsigned)dl < RS) atomicAdd(&scnt[dl], 1);
    }
    __syncthreads();
    int lim = (NN - base < RS) ? (NN - base) : RS;
    for (int i = threadIdx.x; i < lim; i += 512) {
        deg_p[(size_t)c * NN + base + i] = sdeg[i];
        cnt_p[(size_t)c * NN + base + i] = scnt[i];
    }
}

// ---------------- CSR scan (scan1 reduces cnt copies) ----------------
__global__ void k_scan1(const int* __restrict__ cnt_p, int* __restrict__ cnt,
                        int* __restrict__ incl, int* __restrict__ bsum) {
    __shared__ int s[256];
    int i = blockIdx.x * 256 + threadIdx.x;
    int v = 0;
    if (i < NN) {
#pragma unroll
        for (int p = 0; p < NC; p++) v += cnt_p[(size_t)p * NN + i];
        cnt[i] = v;
    }
    s[threadIdx.x] = v;
    __syncthreads();
    for (int off = 1; off < 256; off <<= 1) {
        int t = (threadIdx.x >= off) ? s[threadIdx.x - off] : 0;
        __syncthreads();
        s[threadIdx.x] += t;
        __syncthreads();
    }
    if (i < NN) incl[i] = s[threadIdx.x];
    if (threadIdx.x == 255) bsum[blockIdx.x] = s[255];
}

__global__ void k_scan2(int* __restrict__ bsum) {
    __shared__ int s[256];
    int v = (threadIdx.x < NB) ? bsum[threadIdx.x] : 0;
    s[threadIdx.x] = v;
    __syncthreads();
    for (int off = 1; off < 256; off <<= 1) {
        int t = (threadIdx.x >= off) ? s[threadIdx.x - off] : 0;
        __syncthreads();
        s[threadIdx.x] += t;
        __syncthreads();
    }
    if (threadIdx.x < NB) bsum[threadIdx.x] = s[threadIdx.x];
}

// scan3: row_ptr/cursor + dinv (reduces deg copies)
__global__ void k_scan3(const int* __restrict__ incl, const int* __restrict__ cnt,
                        const int* __restrict__ bsum, int* __restrict__ row_ptr,
                        int* __restrict__ cursor, const float* __restrict__ deg_p,
                        float* __restrict__ dinv) {
    int i = blockIdx.x * 256 + threadIdx.x;
    if (i >= NN) return;
    int off = (blockIdx.x > 0) ? bsum[blockIdx.x - 1] : 0;
    int start = off + incl[i] - cnt[i];
    row_ptr[i] = start;
    cursor[i] = start;
    float d = 0.f;
#pragma unroll
    for (int p = 0; p < NC; p++) d += deg_p[(size_t)p * NN + i];
    dinv[i] = d > 0.f ? rsqrtf(d) : 0.f;
}

// ---------------- scatter: 8B records {src, w} ----------------
__global__ void k_scatter(const int* __restrict__ src, const int* __restrict__ dst,
                          const float* __restrict__ ew, const float* __restrict__ dinv,
                          int* __restrict__ cursor, uint2* __restrict__ csr8) {
    int e = blockIdx.x * 256 + threadIdx.x;
    if (e >= EE) return;
    int d = dst[e], s = src[e];
    int pos = atomicAdd(&cursor[d], 1);
    float w = dinv[s] * ew[e] * dinv[d];
    csr8[pos] = make_uint2((unsigned)s, __float_as_uint(w));
}

// ---------------- build bf16 A level-0 slice: [z | x | ph] at 0..160 ----------------
__global__ void k_build_A(const float* __restrict__ z, const float* __restrict__ x,
                          const float* __restrict__ ph, u16* __restrict__ A) {
    int i = blockIdx.x * 256 + threadIdx.x;
    if (i >= NN * 160) return;
    int n = i / 160, c = i - n * 160;
    float v;
    if (c < 64) v = z[n * 64 + c];
    else if (c < 96) v = x[n * 32 + (c - 64)];
    else v = ph[n * 64 + (c - 96)];
    A[(size_t)n * 480 + c] = f2b(v);
}

// ---------------- merged weight packing (Wp + W3p) ----------------
// A k-layout: [xin(0:96)|ph(96:160)|t1x(160:256)|t1h(256:320)|t2x(320:416)|t2h(416:480)]
__global__ void k_packW_all(const float* __restrict__ Wxz, const float* __restrict__ Wxr,
                            const float* __restrict__ Wxh, const float* __restrict__ Whz,
                            const float* __restrict__ Whr, const float* __restrict__ Whh,
                            u16* __restrict__ Wp, u16* __restrict__ W3p) {
    int idx = blockIdx.x * 256 + threadIdx.x;
    if (idx < 15 * 12 * 512) {
        int j = idx & 7, l = (idx >> 3) & 63;
        int ct = (idx >> 9) % 12, s = (idx >> 9) / 12;
        int k = 32 * s + (l >> 4) * 8 + j;
        int g = ct >> 2;
        int c = 16 * (ct & 3) + (l & 15);
        bool isX;
        int kr;
        if (k < 96)       { isX = true;  kr = k; }
        else if (k < 160) { isX = false; kr = k - 96; }
        else if (k < 256) { isX = true;  kr = 96 + (k - 160); }
        else if (k < 320) { isX = false; kr = 64 + (k - 256); }
        else if (k < 416) { isX = true;  kr = 192 + (k - 320); }
        else              { isX = false; kr = 128 + (k - 416); }
        float val;
        if (isX) {
            const float* W = (g == 0) ? Wxz : ((g == 1) ? Wxr : Wxh);
            val = W[kr * 64 + c];
        } else if (g == 2) {
            val = 0.f;
        } else {
            const float* W = (g == 0) ? Whz : Whr;
            val = W[kr * 64 + c];
        }
        Wp[idx] = f2b(val);
    } else {
        int i2 = idx - 15 * 12 * 512;
        if (i2 >= 6 * 4 * 512) return;
        int j = i2 & 7, l = (i2 >> 3) & 63;
        int ct = (i2 >> 9) & 3, s = i2 >> 11;
        int k = 32 * s + (l >> 4) * 8 + j;
        int ki = k >> 6, kr = k & 63;
        int c = 16 * ct + (l & 15);
        W3p[i2] = f2b(Whh[(ki * 64 + kr) * 64 + c]);
    }
}

// ---------------- bf16 pull propagation ----------------
template <int C, int SCALE, bool HB, int BS, int OS>
__global__ __launch_bounds__(BS) void k_pull(
    const u16* __restrict__ Abase, int inofs, int baseofs, int outofs,
    const uint2* __restrict__ csr8, const int* __restrict__ row_ptr,
    const int* __restrict__ cnt) {
    constexpr int TPR = C / 8;
    int tid = blockIdx.x * BS + threadIdx.x;
    int r = tid / TPR;
    int c8 = (tid - r * TPR) * 8;
    if (r >= NN) return;
    int s0 = row_ptr[r], n = cnt[r];
    float acc[8] = {0.f, 0.f, 0.f, 0.f, 0.f, 0.f, 0.f, 0.f};
    const u16* in = Abase + inofs + c8;
    uint2 e = (n > 0) ? csr8[s0] : make_uint2(0u, 0u);
    for (int j = 0; j < n; j++) {
        uint2 ec = e;
        if (j + 1 < n) e = csr8[s0 + j + 1];
        float w = __uint_as_float(ec.y);
        bf16x8 v = *(const bf16x8*)(in + (size_t)ec.x * OS);
#pragma unroll
        for (int k = 0; k < 8; k++) acc[k] += w * b2f(v[k]);
    }
    const float sc = -(float)SCALE;
    float o[8];
    if (HB) {
        bf16x8 b = *(const bf16x8*)(Abase + (size_t)r * OS + baseofs + c8);
#pragma unroll
        for (int k = 0; k < 8; k++) o[k] = sc * acc[k] - b2f(b[k]);
    } else {
#pragma unroll
        for (int k = 0; k < 8; k++) o[k] = sc * acc[k];
    }
    bf16x8 p;
#pragma unroll
    for (int k = 0; k < 8; k++) p[k] = (short)f2b(o[k]);
    *(bf16x8*)(const_cast<u16*>(Abase) + (size_t)r * OS + outofs + c8) = p;
}

// ---------------- gates GEMM (MFMA): [N,480]x[480,192] -> Zb16, Hx16, A3 slice ----------------
__global__ __launch_bounds__(256) void k_gates_mfma(
    const u16* __restrict__ A, const u16* __restrict__ Wp,
    const float* __restrict__ bxz, const float* __restrict__ bhz,
    const float* __restrict__ bxr, const float* __restrict__ bhr,
    const float* __restrict__ bxh,
    u16* __restrict__ Zb16, u16* __restrict__ Hx16, u16* __restrict__ A3) {
    int wv = (blockIdx.x * 256 + threadIdx.x) >> 6;
    int lane = threadIdx.x & 63;
    int r0 = wv * 16;
    if (r0 >= NN) return;
    int q = lane >> 4, j0 = lane & 15;

    f32x4 acc[12];
#pragma unroll
    for (int i = 0; i < 12; i++) acc[i] = (f32x4){0.f, 0.f, 0.f, 0.f};

    const u16* arow = A + (size_t)(r0 + j0) * 480 + q * 8;
#pragma unroll
    for (int s = 0; s < 15; s++) {
        bf16x8 a = *(const bf16x8*)(arow + 32 * s);
        const u16* bp = Wp + (size_t)(s * 12) * 512 + lane * 8;
#pragma unroll
        for (int ct = 0; ct < 12; ct++) {
            bf16x8 b = *(const bf16x8*)(bp + ct * 512);
            acc[ct] = __builtin_amdgcn_mfma_f32_16x16x32_bf16(a, b, acc[ct], 0, 0, 0);
        }
    }

#pragma unroll
    for (int ct = 0; ct < 4; ct++) {
        int j = 16 * ct + j0;
        float bz = bxz[j] + bhz[j];
        float br = bxr[j] + bhr[j];
        float bh = bxh[j];
#pragma unroll
        for (int reg = 0; reg < 4; reg++) {
            int r = r0 + q * 4 + reg;
            size_t i = (size_t)r * 64 + j;
            float zp = acc[ct][reg] + bz;
            float rp = acc[ct + 4][reg] + br;
            float hp = acc[ct + 8][reg] + bh;
            float zv = 1.f / (1.f + expf(-zp));
            float rv = 1.f / (1.f + expf(-rp));
            float phv = b2f((short)A[(size_t)r * 480 + 96 + j]);
            Zb16[i] = f2b(zv);
            Hx16[i] = f2b(hp);
            A3[(size_t)r * 192 + j] = f2b(rv * phv);
        }
    }
}

// ---------------- final GEMM (MFMA): [N,192]x[192,64] + GRU blend ----------------
__global__ __launch_bounds__(256) void k_final_mfma(
    const u16* __restrict__ A3, const u16* __restrict__ W3p,
    const float* __restrict__ bhh, const u16* __restrict__ Hx16,
    const u16* __restrict__ Zb16, const u16* __restrict__ A,
    float* __restrict__ outh) {
    int wv = (blockIdx.x * 256 + threadIdx.x) >> 6;
    int lane = threadIdx.x & 63;
    int r0 = wv * 16;
    if (r0 >= NN) return;
    int q = lane >> 4, j0 = lane & 15;

    f32x4 acc[4];
#pragma unroll
    for (int i = 0; i < 4; i++) acc[i] = (f32x4){0.f, 0.f, 0.f, 0.f};

    const u16* arow = A3 + (size_t)(r0 + j0) * 192 + q * 8;
#pragma unroll
    for (int s = 0; s < 6; s++) {
        bf16x8 a = *(const bf16x8*)(arow + 32 * s);
        const u16* bp = W3p + (size_t)(s * 4) * 512 + lane * 8;
#pragma unroll
        for (int ct = 0; ct < 4; ct++) {
            bf16x8 b = *(const bf16x8*)(bp + ct * 512);
            acc[ct] = __builtin_amdgcn_mfma_f32_16x16x32_bf16(a, b, acc[ct], 0, 0, 0);
        }
    }

#pragma unroll
    for (int ct = 0; ct < 4; ct++) {
        int j = 16 * ct + j0;
        float bh = bhh[j];
#pragma unroll
        for (int reg = 0; reg < 4; reg++) {
            int r = r0 + q * 4 + reg;
            size_t i = (size_t)r * 64 + j;
            float ht = tanhf(b2f((short)Hx16[i]) + acc[ct][reg] + bh);
            float zv = b2f((short)Zb16[i]);
            float phv = b2f((short)A[(size_t)r * 480 + 96 + j]);
            outh[i] = zv * phv + (1.f - zv) * ht;
        }
    }
}

// ---------------- tail: graph emb (binary search over sorted batch) + global emb ----------------
__global__ __launch_bounds__(256) void k_tail(
    const float* __restrict__ z, const int* __restrict__ batch,
    const float* __restrict__ u, const float* __restrict__ Wg,
    const float* __restrict__ bg, float* __restrict__ out) {
    int b = (blockIdx.x * 256 + threadIdx.x) >> 6;
    int lane = threadIdx.x & 63;
    if (b >= BB) return;
    // lower_bound(batch, b) and lower_bound(batch, b+1)
    int lo = 0, hi = NN;
    while (lo < hi) {
        int m = (lo + hi) >> 1;
        if (batch[m] < b) lo = m + 1; else hi = m;
    }
    int start = lo;
    hi = NN;
    while (lo < hi) {
        int m = (lo + hi) >> 1;
        if (batch[m] < b + 1) lo = m + 1; else hi = m;
    }
    int end = lo;
    float acc = 0.f;
    for (int n = start; n < end; n++) acc += z[(size_t)n * 64 + lane];
    float g = bg[lane];
    const float* ur = u + (size_t)b * 64;
    for (int k = 0; k < 64; k++) g += ur[k] * Wg[k * 64 + lane];
    g = fmaxf(g, 0.f);
    out[(size_t)b * 128 + lane] = acc;
    out[(size_t)b * 128 + 64 + lane] = g;
}

extern "C" void kernel_launch(void* const* d_in, const int* in_sizes, int n_in,
                              void* d_out, int out_size, void* d_ws, size_t ws_size,
                              hipStream_t stream) {
    const float* x  = (const float*)d_in[0];
    const float* u  = (const float*)d_in[1];
    const float* z  = (const float*)d_in[2];
    const int*   ei = (const int*)d_in[3];
    const float* ew = (const float*)d_in[4];
    const int* batch = (const int*)d_in[5];
    const float* ph = (const float*)d_in[7];
    const float *Wxz = (const float*)d_in[8],  *bxz = (const float*)d_in[9];
    const float *Whz = (const float*)d_in[10], *bhz = (const float*)d_in[11];
    const float *Wxr = (const float*)d_in[12], *bxr = (const float*)d_in[13];
    const float *Whr = (const float*)d_in[14], *bhr = (const float*)d_in[15];
    const float *Wxh = (const float*)d_in[16], *bxh = (const float*)d_in[17];
    const float *Whh = (const float*)d_in[18], *bhh = (const float*)d_in[19];
    const float *Wg  = (const float*)d_in[20], *bg  = (const float*)d_in[21];
    const int* src = ei;
    const int* dst = ei + EE;

    char* wsb = (char*)d_ws;
    size_t o = 0;
    auto alloc = [&](size_t bytes) {
        void* p = wsb + o;
        o += (bytes + 255) & ~(size_t)255;
        return p;
    };
    float* deg_p   = (float*)alloc((size_t)NC * NN * 4);  // fully overwritten, no memset
    int*   cnt_p   = (int*)alloc((size_t)NC * NN * 4);    // fully overwritten, no memset
    int*   cnt     = (int*)alloc(NN * 4);
    int*   incl    = (int*)alloc(NN * 4);
    int*   row_ptr = (int*)alloc(NN * 4);
    int*   cursor  = (int*)alloc(NN * 4);
    float* dinv    = (float*)alloc(NN * 4);
    int*   bsum    = (int*)alloc(256 * 4);
    uint2* csr8    = (uint2*)alloc((size_t)EE * 8);
    u16*   Zb16 = (u16*)alloc((size_t)NN * 64 * 2);
    u16*   Hx16 = (u16*)alloc((size_t)NN * 64 * 2);
    u16*   A    = (u16*)alloc((size_t)NN * 480 * 2);
    u16*   A3   = (u16*)alloc((size_t)NN * 192 * 2);
    u16*   Wp   = (u16*)alloc(15 * 12 * 512 * 2);
    u16*   W3p  = (u16*)alloc(6 * 4 * 512 * 2);

    float* outF = (float*)d_out;               // [B,128]
    float* outH = outF + (size_t)BB * 128;     // [N,64]

    const int BLK = 256;
    const int gE = (EE + BLK - 1) / BLK;
    const int gA = (NN * 160 + BLK - 1) / BLK;
    const int gPull160 = (NN + 15) / 16;  // 320 thr, 20 thr/row -> 16 rows/blk
    const int gPull64 = (NN + 31) / 32;   // 256 thr, 8 thr/row -> 32 rows/blk
    const int gMFMA = (3125 + 3) / 4;
    const int gPack = (15 * 12 * 512 + 6 * 4 * 512 + BLK - 1) / BLK;

    // 0. independent prep
    k_packW_all<<<gPack, BLK, 0, stream>>>(Wxz, Wxr, Wxh, Whz, Whr, Whh, Wp, W3p);
    k_build_A<<<gA, BLK, 0, stream>>>(z, x, ph, A);

    // 1. degree + indegree: LDS histograms, no global atomics, no memset
    k_degcnt_lds<<<NR * NC, 512, 0, stream>>>(src, dst, ew, deg_p, cnt_p);

    // 2. CSR scan (reduce copies; dinv in scan3), scatter 8B records
    k_scan1<<<NB, 256, 0, stream>>>(cnt_p, cnt, incl, bsum);
    k_scan2<<<1, 256, 0, stream>>>(bsum);
    k_scan3<<<NB, 256, 0, stream>>>(incl, cnt, bsum, row_ptr, cursor, deg_p, dinv);
    k_scatter<<<gE, BLK, 0, stream>>>(src, dst, ew, dinv, cursor, csr8);

    // 3. Chebyshev bases, merged 160-ch pulls: t1 = -prop(t0); t2 = -2*prop(t1) - t0
    k_pull<160, 1, false, 320, 480><<<gPull160, 320, 0, stream>>>(A, 0, 0, 160, csr8, row_ptr, cnt);
    k_pull<160, 2, true, 320, 480><<<gPull160, 320, 0, stream>>>(A, 160, 0, 320, csr8, row_ptr, cnt);

    // 4. gates GEMM -> Zb16, Hx16, A3 slice 0 (hr)
    k_gates_mfma<<<gMFMA, BLK, 0, stream>>>(A, Wp, bxz, bhz, bxr, bhr, bxh, Zb16, Hx16, A3);

    // 5. Chebyshev basis for hr (in A3)
    k_pull<64, 1, false, 256, 192><<<gPull64, 256, 0, stream>>>(A3, 0, 0, 64, csr8, row_ptr, cnt);
    k_pull<64, 2, true, 256, 192><<<gPull64, 256, 0, stream>>>(A3, 64, 0, 128, csr8, row_ptr, cnt);

    // 6. candidate GEMM + GRU blend -> h out
    k_final_mfma<<<gMFMA, BLK, 0, stream>>>(A3, W3p, bhh, Hx16, Zb16, A, outH);

    // 7. tail: graph emb (binary search) + global emb -> fused out
    k_tail<<<(BB * 64 + BLK - 1) / BLK, BLK, 0, stream>>>(z, batch, u, Wg, bg, outF);
}